// Round 2
// baseline (1522.417 us; speedup 1.0000x reference)
//
#include <hip/hip_runtime.h>
#include <hip/hip_bf16.h>

// Problem constants (from reference)
#define NODES 50000
#define NEDGE 800000
#define NE2   850000   // NEDGE + NODES self-loops
#define INDIM 128
#define F1    256      // HEADS*HID
#define HEADS 4
#define HID   64
#define OUTD  64

// ---------------- Layer 1 GEMM: xp1 = x @ W1, fused s_src1/s_dst1 ----------------
// one block (256 thr) per node row; x row staged in LDS; thread t -> output col t
__global__ void k_gemm1(const float* __restrict__ x, const float* __restrict__ W1,
                        const float* __restrict__ as1, const float* __restrict__ ad1,
                        float* __restrict__ xp1, float* __restrict__ ssrc,
                        float* __restrict__ sdst)
{
    __shared__ float xs[INDIM];
    const int n = blockIdx.x;
    const int t = threadIdx.x;
    if (t < INDIM) xs[t] = x[n * INDIM + t];
    __syncthreads();
    float acc = 0.f;
#pragma unroll 8
    for (int k = 0; k < INDIM; ++k)
        acc = fmaf(xs[k], W1[k * F1 + t], acc);
    xp1[n * F1 + t] = acc;

    const int h = t >> 6, c = t & 63;   // wave == head (64 consecutive lanes)
    float ps = acc * as1[h * HID + c];
    float pd = acc * ad1[h * HID + c];
#pragma unroll
    for (int off = 32; off; off >>= 1) {
        ps += __shfl_down(ps, off);
        pd += __shfl_down(pd, off);
    }
    if (c == 0) { ssrc[n * HEADS + h] = ps; sdst[n * HEADS + h] = pd; }
}

// ---------------- Edge denom pass (layer 1): den[d,h] += exp(lrelu(ssrc[s,h]+sdst[d,h])) ----------------
__global__ void k_edge1_denom(const int* __restrict__ ei,
                              const float* __restrict__ ssrc,
                              const float* __restrict__ sdst,
                              float* __restrict__ den)
{
    int i = blockIdx.x * 256 + threadIdx.x;
    if (i >= NE2) return;
    int s, d;
    if (i < NEDGE) { s = ei[i]; d = ei[NEDGE + i]; } else { s = d = i - NEDGE; }
#pragma unroll
    for (int h = 0; h < HEADS; ++h) {
        float e = ssrc[s * HEADS + h] + sdst[d * HEADS + h];
        e = e > 0.f ? e : 0.2f * e;
        atomicAdd(&den[d * HEADS + h], __expf(e));
    }
}

// ---------------- rden = 1/(den + 1e-16), in place ----------------
__global__ void k_rcp(float* __restrict__ p, int n)
{
    int i = blockIdx.x * 256 + threadIdx.x;
    if (i < n) p[i] = 1.0f / (p[i] + 1e-16f);
}

// ---------------- Layer 1 agg: hbuf[d] += alpha * xp1[s] ----------------
// one wave (64 lanes) per edge; lane = channel within head; 4 heads looped
__global__ void k_edge1_agg(const int* __restrict__ ei, const float* __restrict__ xp1,
                            const float* __restrict__ ssrc, const float* __restrict__ sdst,
                            const float* __restrict__ rden, float* __restrict__ agg)
{
    int gid = blockIdx.x * 256 + threadIdx.x;
    int e = gid >> 6;
    int lane = threadIdx.x & 63;
    if (e >= NE2) return;
    int s, d;
    if (e < NEDGE) { s = ei[e]; d = ei[NEDGE + e]; } else { s = d = e - NEDGE; }
#pragma unroll
    for (int h = 0; h < HEADS; ++h) {
        float ev = ssrc[s * HEADS + h] + sdst[d * HEADS + h];   // wave-uniform
        ev = ev > 0.f ? ev : 0.2f * ev;
        float alpha = __expf(ev) * rden[d * HEADS + h];
        atomicAdd(&agg[d * F1 + h * HID + lane], alpha * xp1[s * F1 + h * HID + lane]);
    }
}

// ---------------- Layer 1 epilogue: h = relu(agg + bias1), in place ----------------
__global__ void k_relu_bias(float* __restrict__ hbuf, const float* __restrict__ bias)
{
    int i = blockIdx.x * 256 + threadIdx.x;
    if (i >= NODES * F1) return;
    float v = hbuf[i] + bias[i & (F1 - 1)];
    hbuf[i] = v > 0.f ? v : 0.f;
}

// ---------------- Layer 2 GEMM: xp2 = h @ W2, fused s_src2/s_dst2 ----------------
// block 256 = 4 waves; one wave per node row; h row staged in LDS
__global__ void k_gemm2(const float* __restrict__ hbuf, const float* __restrict__ W2,
                        const float* __restrict__ as2, const float* __restrict__ ad2,
                        float* __restrict__ xp2, float* __restrict__ ssrc,
                        float* __restrict__ sdst)
{
    __shared__ float hs[4][F1];
    const int w = threadIdx.x >> 6, lane = threadIdx.x & 63;
    const int n = blockIdx.x * 4 + w;
    if (n < NODES) {
#pragma unroll
        for (int j = 0; j < 4; ++j)
            hs[w][j * 64 + lane] = hbuf[n * F1 + j * 64 + lane];
    }
    __syncthreads();
    if (n >= NODES) return;
    float acc = 0.f;
#pragma unroll 8
    for (int k = 0; k < F1; ++k)
        acc = fmaf(hs[w][k], W2[k * OUTD + lane], acc);
    xp2[n * OUTD + lane] = acc;

    float ps = acc * as2[lane];
    float pd = acc * ad2[lane];
#pragma unroll
    for (int off = 32; off; off >>= 1) {
        ps += __shfl_down(ps, off);
        pd += __shfl_down(pd, off);
    }
    if (lane == 0) { ssrc[n] = ps; sdst[n] = pd; }
}

// ---------------- Layer 2 denom ----------------
__global__ void k_edge2_denom(const int* __restrict__ ei,
                              const float* __restrict__ ssrc,
                              const float* __restrict__ sdst,
                              float* __restrict__ den)
{
    int i = blockIdx.x * 256 + threadIdx.x;
    if (i >= NE2) return;
    int s, d;
    if (i < NEDGE) { s = ei[i]; d = ei[NEDGE + i]; } else { s = d = i - NEDGE; }
    float e = ssrc[s] + sdst[d];
    e = e > 0.f ? e : 0.2f * e;
    atomicAdd(&den[d], __expf(e));
}

// ---------------- Layer 2 agg ----------------
__global__ void k_edge2_agg(const int* __restrict__ ei, const float* __restrict__ xp2,
                            const float* __restrict__ ssrc, const float* __restrict__ sdst,
                            const float* __restrict__ rden, float* __restrict__ agg)
{
    int gid = blockIdx.x * 256 + threadIdx.x;
    int e = gid >> 6;
    int lane = threadIdx.x & 63;
    if (e >= NE2) return;
    int s, d;
    if (e < NEDGE) { s = ei[e]; d = ei[NEDGE + e]; } else { s = d = e - NEDGE; }
    float ev = ssrc[s] + sdst[d];
    ev = ev > 0.f ? ev : 0.2f * ev;
    float alpha = __expf(ev) * rden[d];
    atomicAdd(&agg[d * OUTD + lane], alpha * xp2[s * OUTD + lane]);
}

// ---------------- Output: out = agg2 + bias2 (f32) ----------------
__global__ void k_out(const float* __restrict__ agg, const float* __restrict__ bias,
                      float* __restrict__ out)
{
    int i = blockIdx.x * 256 + threadIdx.x;
    if (i >= NODES * OUTD) return;
    out[i] = agg[i] + bias[i & (OUTD - 1)];
}

extern "C" void kernel_launch(void* const* d_in, const int* in_sizes, int n_in,
                              void* d_out, int out_size, void* d_ws, size_t ws_size,
                              hipStream_t stream)
{
    (void)in_sizes; (void)n_in; (void)out_size; (void)ws_size;
    const float* x   = (const float*)d_in[0];
    const int*   ei  = (const int*)d_in[1];
    const float* W1  = (const float*)d_in[2];
    const float* as1 = (const float*)d_in[3];
    const float* ad1 = (const float*)d_in[4];
    const float* b1  = (const float*)d_in[5];
    const float* W2  = (const float*)d_in[6];
    const float* as2 = (const float*)d_in[7];
    const float* ad2 = (const float*)d_in[8];
    const float* b2  = (const float*)d_in[9];
    float* out = (float*)d_out;

    // workspace layout (floats): ~118.2 MB total; agg2 aliases dead xp1
    float* ws    = (float*)d_ws;
    float* xp1   = ws;                              // N*256 (later reused as agg2)
    float* hbuf  = xp1 + (size_t)NODES * F1;        // N*256 (agg1 -> h)
    float* xp2   = hbuf + (size_t)NODES * F1;       // N*64
    float* ssrc1 = xp2 + (size_t)NODES * OUTD;      // N*4
    float* sdst1 = ssrc1 + (size_t)NODES * HEADS;   // N*4
    float* den1  = sdst1 + (size_t)NODES * HEADS;   // N*4
    float* ssrc2 = den1 + (size_t)NODES * HEADS;    // N
    float* sdst2 = ssrc2 + (size_t)NODES;           // N
    float* den2  = sdst2 + (size_t)NODES;           // N
    float* agg2  = xp1;                             // alias: xp1 dead after k_edge1_agg

    hipMemsetAsync(hbuf, 0, sizeof(float) * (size_t)NODES * F1, stream);
    hipMemsetAsync(den1, 0, sizeof(float) * (size_t)NODES * HEADS, stream);
    hipMemsetAsync(den2, 0, sizeof(float) * (size_t)NODES, stream);

    // ---- layer 1 ----
    k_gemm1<<<NODES, 256, 0, stream>>>(x, W1, as1, ad1, xp1, ssrc1, sdst1);
    k_edge1_denom<<<(NE2 + 255) / 256, 256, 0, stream>>>(ei, ssrc1, sdst1, den1);
    k_rcp<<<(NODES * HEADS + 255) / 256, 256, 0, stream>>>(den1, NODES * HEADS);
    k_edge1_agg<<<((size_t)NE2 * 64 + 255) / 256, 256, 0, stream>>>(ei, xp1, ssrc1, sdst1, den1, hbuf);
    k_relu_bias<<<(NODES * F1 + 255) / 256, 256, 0, stream>>>(hbuf, b1);

    // ---- layer 2 ----
    k_gemm2<<<(NODES + 3) / 4, 256, 0, stream>>>(hbuf, W2, as2, ad2, xp2, ssrc2, sdst2);
    k_edge2_denom<<<(NE2 + 255) / 256, 256, 0, stream>>>(ei, ssrc2, sdst2, den2);
    k_rcp<<<(NODES + 255) / 256, 256, 0, stream>>>(den2, NODES);
    hipMemsetAsync(agg2, 0, sizeof(float) * (size_t)NODES * OUTD, stream);  // xp1 now dead
    k_edge2_agg<<<((size_t)NE2 * 64 + 255) / 256, 256, 0, stream>>>(ei, xp2, ssrc2, sdst2, den2, agg2);
    k_out<<<(NODES * OUTD + 255) / 256, 256, 0, stream>>>(agg2, b2, out);
}

// Round 3
// 528.672 us; speedup vs baseline: 2.8797x; 2.8797x over previous
//
#include <hip/hip_runtime.h>
#include <hip/hip_bf16.h>

// Problem constants (from reference)
#define NODES 50000
#define NEDGE 800000
#define NE2   850000   // NEDGE + NODES self-loops
#define INDIM 128
#define F1    256      // HEADS*HID
#define HEADS 4
#define HID   64
#define OUTD  64
#define NBLK_SCAN 196  // ceil(NODES/256)

// ================= CSR build =================
__global__ void k_hist(const int* __restrict__ ei, int* __restrict__ deg)
{
    int i = blockIdx.x * 256 + threadIdx.x;
    if (i >= NE2) return;
    int d = (i < NEDGE) ? ei[NEDGE + i] : (i - NEDGE);
    atomicAdd(&deg[d], 1);
}

// per-256-chunk exclusive scan; chunk total to bsum
__global__ void k_scan1(const int* __restrict__ deg, int* __restrict__ excl,
                        int* __restrict__ bsum)
{
    __shared__ int sh[256];
    int t = threadIdx.x;
    int i = blockIdx.x * 256 + t;
    int v = (i < NODES) ? deg[i] : 0;
    sh[t] = v; __syncthreads();
    for (int off = 1; off < 256; off <<= 1) {
        int tv = (t >= off) ? sh[t - off] : 0;
        __syncthreads();
        sh[t] += tv;
        __syncthreads();
    }
    if (i < NODES) excl[i] = sh[t] - v;
    if (t == 255) bsum[blockIdx.x] = sh[255];
}

// exclusive scan of the 196 block sums, in place (single block)
__global__ void k_scan2(int* __restrict__ bsum)
{
    __shared__ int sh[256];
    int t = threadIdx.x;
    int v = (t < NBLK_SCAN) ? bsum[t] : 0;
    sh[t] = v; __syncthreads();
    for (int off = 1; off < 256; off <<= 1) {
        int tv = (t >= off) ? sh[t - off] : 0;
        __syncthreads();
        sh[t] += tv;
        __syncthreads();
    }
    if (t < NBLK_SCAN) bsum[t] = sh[t] - v;
}

__global__ void k_scan3(int* __restrict__ row_ptr, const int* __restrict__ bsum,
                        int* __restrict__ cursor)
{
    int i = blockIdx.x * 256 + threadIdx.x;
    if (i < NODES) {
        int v = row_ptr[i] + bsum[i >> 8];
        row_ptr[i] = v;
        cursor[i] = v;
    }
    if (i == 0) row_ptr[NODES] = NE2;
}

__global__ void k_scatter(const int* __restrict__ ei, int* __restrict__ cursor,
                          int* __restrict__ csr_src)
{
    int i = blockIdx.x * 256 + threadIdx.x;
    if (i >= NE2) return;
    int s, d;
    if (i < NEDGE) { s = ei[i]; d = ei[NEDGE + i]; } else { s = d = i - NEDGE; }
    int pos = atomicAdd(&cursor[d], 1);
    csr_src[pos] = s;
}

// ================= Layer 1 GEMM: xp1 = x @ W1 (+fused attention scores) ========
// 8 nodes per block (50000 = 8*6250); thread t -> out col t; acc[8] in regs
__global__ __launch_bounds__(256) void k_gemm1(
    const float* __restrict__ x, const float* __restrict__ W1,
    const float* __restrict__ as1, const float* __restrict__ ad1,
    float* __restrict__ xp1, float* __restrict__ ssrc, float* __restrict__ sdst)
{
    __shared__ float xs[8][INDIM];
    const int nb = blockIdx.x * 8, t = threadIdx.x;
#pragma unroll
    for (int r = 0; r < 4; ++r) {
        int idx = r * 256 + t;
        xs[idx >> 7][idx & 127] = x[nb * INDIM + idx];
    }
    __syncthreads();
    float acc[8] = {0.f, 0.f, 0.f, 0.f, 0.f, 0.f, 0.f, 0.f};
#pragma unroll 4
    for (int k = 0; k < INDIM; ++k) {
        float wv = W1[k * F1 + t];
#pragma unroll
        for (int r = 0; r < 8; ++r) acc[r] = fmaf(xs[r][k], wv, acc[r]);
    }
    const float a_s = as1[t], a_d = ad1[t];
    const int h = t >> 6, c = t & 63;
#pragma unroll
    for (int r = 0; r < 8; ++r) {
        xp1[(nb + r) * F1 + t] = acc[r];
        float ps = acc[r] * a_s, pd = acc[r] * a_d;
#pragma unroll
        for (int off = 32; off; off >>= 1) {
            ps += __shfl_down(ps, off);
            pd += __shfl_down(pd, off);
        }
        if (c == 0) {
            ssrc[(nb + r) * HEADS + h] = ps;
            sdst[(nb + r) * HEADS + h] = pd;
        }
    }
}

// ===== Layer 1 fused softmax+aggregate (gather, no atomics) =====
// one block per dst node; thread t = channel t; h = t>>6
// out = relu( sum_e exp(e)*xp1[src] / (sum_e exp(e) + eps) + bias )
__global__ __launch_bounds__(256) void k_agg1(
    const int* __restrict__ row_ptr, const int* __restrict__ csr_src,
    const float* __restrict__ ssrc, const float* __restrict__ sdst,
    const float* __restrict__ xp1, const float* __restrict__ bias,
    float* __restrict__ hbuf)
{
    const int n = blockIdx.x, t = threadIdx.x, h = t >> 6;
    const float sd = sdst[n * HEADS + h];
    int j = row_ptr[n];
    const int jend = row_ptr[n + 1];
    float den = 0.f, acc = 0.f;
    for (; j + 1 < jend; j += 2) {
        int s0 = csr_src[j], s1 = csr_src[j + 1];
        float e0 = ssrc[s0 * HEADS + h] + sd; e0 = e0 > 0.f ? e0 : 0.2f * e0;
        float e1 = ssrc[s1 * HEADS + h] + sd; e1 = e1 > 0.f ? e1 : 0.2f * e1;
        float x0 = __expf(e0), x1 = __expf(e1);
        den += x0 + x1;
        acc = fmaf(x0, xp1[(size_t)s0 * F1 + t], acc);
        acc = fmaf(x1, xp1[(size_t)s1 * F1 + t], acc);
    }
    if (j < jend) {
        int s0 = csr_src[j];
        float e0 = ssrc[s0 * HEADS + h] + sd; e0 = e0 > 0.f ? e0 : 0.2f * e0;
        float x0 = __expf(e0);
        den += x0;
        acc = fmaf(x0, xp1[(size_t)s0 * F1 + t], acc);
    }
    float v = acc / (den + 1e-16f) + bias[t];
    hbuf[n * F1 + t] = v > 0.f ? v : 0.f;
}

// ================= Layer 2 GEMM: xp2 = h @ W2 (+fused scores) ==================
// 16 nodes per block (50000 = 16*3125); wave w handles 4 nodes; lane = col
__global__ __launch_bounds__(256) void k_gemm2(
    const float* __restrict__ hbuf, const float* __restrict__ W2,
    const float* __restrict__ as2, const float* __restrict__ ad2,
    float* __restrict__ xp2, float* __restrict__ ssrc, float* __restrict__ sdst)
{
    __shared__ float hs[16][F1];
    const int nb = blockIdx.x * 16, t = threadIdx.x;
#pragma unroll
    for (int r = 0; r < 16; ++r) {
        int idx = r * 256 + t;
        hs[idx >> 8][idx & 255] = hbuf[nb * F1 + idx];
    }
    __syncthreads();
    const int w = t >> 6, lane = t & 63;
    float acc[4] = {0.f, 0.f, 0.f, 0.f};
#pragma unroll 2
    for (int k = 0; k < F1; ++k) {
        float wv = W2[k * OUTD + lane];
#pragma unroll
        for (int j = 0; j < 4; ++j) acc[j] = fmaf(hs[w * 4 + j][k], wv, acc[j]);
    }
    const float a_s = as2[lane], a_d = ad2[lane];
#pragma unroll
    for (int j = 0; j < 4; ++j) {
        int n = nb + w * 4 + j;
        xp2[n * OUTD + lane] = acc[j];
        float ps = acc[j] * a_s, pd = acc[j] * a_d;
#pragma unroll
        for (int off = 32; off; off >>= 1) {
            ps += __shfl_down(ps, off);
            pd += __shfl_down(pd, off);
        }
        if (lane == 0) { ssrc[n] = ps; sdst[n] = pd; }
    }
}

// ===== Layer 2 fused softmax+aggregate+bias -> d_out =====
// 4 nodes per block (one per wave); lane = channel
__global__ __launch_bounds__(256) void k_agg2(
    const int* __restrict__ row_ptr, const int* __restrict__ csr_src,
    const float* __restrict__ ssrc, const float* __restrict__ sdst,
    const float* __restrict__ xp2, const float* __restrict__ bias,
    float* __restrict__ out)
{
    const int w = threadIdx.x >> 6, lane = threadIdx.x & 63;
    const int n = blockIdx.x * 4 + w;
    const float sd = sdst[n];
    int j = row_ptr[n];
    const int jend = row_ptr[n + 1];
    float den = 0.f, acc = 0.f;
    for (; j + 1 < jend; j += 2) {
        int s0 = csr_src[j], s1 = csr_src[j + 1];
        float e0 = ssrc[s0] + sd; e0 = e0 > 0.f ? e0 : 0.2f * e0;
        float e1 = ssrc[s1] + sd; e1 = e1 > 0.f ? e1 : 0.2f * e1;
        float x0 = __expf(e0), x1 = __expf(e1);
        den += x0 + x1;
        acc = fmaf(x0, xp2[(size_t)s0 * OUTD + lane], acc);
        acc = fmaf(x1, xp2[(size_t)s1 * OUTD + lane], acc);
    }
    if (j < jend) {
        int s0 = csr_src[j];
        float e0 = ssrc[s0] + sd; e0 = e0 > 0.f ? e0 : 0.2f * e0;
        float x0 = __expf(e0);
        den += x0;
        acc = fmaf(x0, xp2[(size_t)s0 * OUTD + lane], acc);
    }
    out[n * OUTD + lane] = acc / (den + 1e-16f) + bias[lane];
}

extern "C" void kernel_launch(void* const* d_in, const int* in_sizes, int n_in,
                              void* d_out, int out_size, void* d_ws, size_t ws_size,
                              hipStream_t stream)
{
    (void)in_sizes; (void)n_in; (void)out_size; (void)ws_size;
    const float* x   = (const float*)d_in[0];
    const int*   ei  = (const int*)d_in[1];
    const float* W1  = (const float*)d_in[2];
    const float* as1 = (const float*)d_in[3];
    const float* ad1 = (const float*)d_in[4];
    const float* b1  = (const float*)d_in[5];
    const float* W2  = (const float*)d_in[6];
    const float* as2 = (const float*)d_in[7];
    const float* ad2 = (const float*)d_in[8];
    const float* b2  = (const float*)d_in[9];
    float* out = (float*)d_out;

    // workspace layout (~108 MB, 4B units)
    float* ws    = (float*)d_ws;
    float* xp1   = ws;                              // N*F1 (xp2 aliases this later)
    float* hbuf  = xp1 + (size_t)NODES * F1;        // N*F1
    float* ssrc1 = hbuf + (size_t)NODES * F1;       // N*4
    float* sdst1 = ssrc1 + (size_t)NODES * HEADS;   // N*4
    float* ssrc2 = sdst1 + (size_t)NODES * HEADS;   // N
    float* sdst2 = ssrc2 + (size_t)NODES;           // N
    int* deg     = (int*)(sdst2 + (size_t)NODES);   // N
    int* row_ptr = deg + NODES;                     // N+1
    int* bsum    = row_ptr + NODES + 1;             // 256
    int* cursor  = bsum + 256;                      // N
    int* csr_src = cursor + NODES;                  // NE2
    float* xp2   = xp1;                             // alias: xp1 dead after k_agg1

    // ---- CSR build (dst-sorted) ----
    hipMemsetAsync(deg, 0, sizeof(int) * NODES, stream);
    k_hist<<<(NE2 + 255) / 256, 256, 0, stream>>>(ei, deg);
    k_scan1<<<NBLK_SCAN, 256, 0, stream>>>(deg, row_ptr, bsum);
    k_scan2<<<1, 256, 0, stream>>>(bsum);
    k_scan3<<<NBLK_SCAN, 256, 0, stream>>>(row_ptr, bsum, cursor);
    k_scatter<<<(NE2 + 255) / 256, 256, 0, stream>>>(ei, cursor, csr_src);

    // ---- layer 1 ----
    k_gemm1<<<NODES / 8, 256, 0, stream>>>(x, W1, as1, ad1, xp1, ssrc1, sdst1);
    k_agg1<<<NODES, 256, 0, stream>>>(row_ptr, csr_src, ssrc1, sdst1, xp1, b1, hbuf);

    // ---- layer 2 ----
    k_gemm2<<<NODES / 16, 256, 0, stream>>>(hbuf, W2, as2, ad2, xp2, ssrc2, sdst2);
    k_agg2<<<NODES / 4, 256, 0, stream>>>(row_ptr, csr_src, ssrc2, sdst2, xp2, b2, out);
}

// Round 4
// 465.993 us; speedup vs baseline: 3.2670x; 1.1345x over previous
//
#include <hip/hip_runtime.h>
#include <hip/hip_bf16.h>
#include <hip/hip_fp16.h>

// Problem constants (from reference)
#define NODES 50000
#define NEDGE 800000
#define NE2   850000   // NEDGE + NODES self-loops
#define INDIM 128
#define F1    256      // HEADS*HID
#define HEADS 4
#define HID   64
#define OUTD  64
#define NBLK_SCAN 196  // ceil(NODES/256)

// ================= CSR build =================
__global__ void k_hist(const int* __restrict__ ei, int* __restrict__ deg)
{
    int i = blockIdx.x * 256 + threadIdx.x;
    if (i >= NE2) return;
    int d = (i < NEDGE) ? ei[NEDGE + i] : (i - NEDGE);
    atomicAdd(&deg[d], 1);
}

__global__ void k_scan1(const int* __restrict__ deg, int* __restrict__ excl,
                        int* __restrict__ bsum)
{
    __shared__ int sh[256];
    int t = threadIdx.x;
    int i = blockIdx.x * 256 + t;
    int v = (i < NODES) ? deg[i] : 0;
    sh[t] = v; __syncthreads();
    for (int off = 1; off < 256; off <<= 1) {
        int tv = (t >= off) ? sh[t - off] : 0;
        __syncthreads();
        sh[t] += tv;
        __syncthreads();
    }
    if (i < NODES) excl[i] = sh[t] - v;
    if (t == 255) bsum[blockIdx.x] = sh[255];
}

__global__ void k_scan2(int* __restrict__ bsum)
{
    __shared__ int sh[256];
    int t = threadIdx.x;
    int v = (t < NBLK_SCAN) ? bsum[t] : 0;
    sh[t] = v; __syncthreads();
    for (int off = 1; off < 256; off <<= 1) {
        int tv = (t >= off) ? sh[t - off] : 0;
        __syncthreads();
        sh[t] += tv;
        __syncthreads();
    }
    if (t < NBLK_SCAN) bsum[t] = sh[t] - v;
}

__global__ void k_scan3(int* __restrict__ row_ptr, const int* __restrict__ bsum,
                        int* __restrict__ cursor)
{
    int i = blockIdx.x * 256 + threadIdx.x;
    if (i < NODES) {
        int v = row_ptr[i] + bsum[i >> 8];
        row_ptr[i] = v;
        cursor[i] = v;
    }
    if (i == 0) row_ptr[NODES] = NE2;
}

__global__ void k_scatter(const int* __restrict__ ei, int* __restrict__ cursor,
                          int* __restrict__ csr_src)
{
    int i = blockIdx.x * 256 + threadIdx.x;
    if (i >= NE2) return;
    int s, d;
    if (i < NEDGE) { s = ei[i]; d = ei[NEDGE + i]; } else { s = d = i - NEDGE; }
    int pos = atomicAdd(&cursor[d], 1);
    csr_src[pos] = s;
}

// ================= Layer 1 GEMM: xp1 = x @ W1 (+fused attention scores) ========
// 8 nodes per block; thread t -> out col t; acc[8] in regs; xp1 stored fp16
__global__ __launch_bounds__(256) void k_gemm1(
    const float* __restrict__ x, const float* __restrict__ W1,
    const float* __restrict__ as1, const float* __restrict__ ad1,
    __half* __restrict__ xp1h, float* __restrict__ ssrc, float* __restrict__ sdst)
{
    __shared__ float xs[8][INDIM];
    const int nb = blockIdx.x * 8, t = threadIdx.x;
#pragma unroll
    for (int r = 0; r < 4; ++r) {
        int idx = r * 256 + t;
        xs[idx >> 7][idx & 127] = x[nb * INDIM + idx];
    }
    __syncthreads();
    float acc[8] = {0.f, 0.f, 0.f, 0.f, 0.f, 0.f, 0.f, 0.f};
#pragma unroll 4
    for (int k = 0; k < INDIM; ++k) {
        float wv = W1[k * F1 + t];
#pragma unroll
        for (int r = 0; r < 8; ++r) acc[r] = fmaf(xs[r][k], wv, acc[r]);
    }
    const float a_s = as1[t], a_d = ad1[t];
    const int h = t >> 6, c = t & 63;
#pragma unroll
    for (int r = 0; r < 8; ++r) {
        xp1h[(size_t)(nb + r) * F1 + t] = __float2half(acc[r]);
        float ps = acc[r] * a_s, pd = acc[r] * a_d;
#pragma unroll
        for (int off = 32; off; off >>= 1) {
            ps += __shfl_down(ps, off);
            pd += __shfl_down(pd, off);
        }
        if (c == 0) {
            ssrc[(nb + r) * HEADS + h] = ps;
            sdst[(nb + r) * HEADS + h] = pd;
        }
    }
}

// ===== Layer 1 fused softmax+aggregate (gather; shfl-broadcast scores) =====
// one block per dst node; thread t = channel t; wave = head (h = t>>6)
// chunked: phase A lane l computes exp for edge (base+l); phase B shfl-bcast
__global__ __launch_bounds__(256) void k_agg1(
    const int* __restrict__ row_ptr, const int* __restrict__ csr_src,
    const float* __restrict__ ssrc, const float* __restrict__ sdst,
    const __half* __restrict__ xp1h, const float* __restrict__ bias,
    float* __restrict__ hbuf)
{
    const int n = blockIdx.x, t = threadIdx.x, h = t >> 6, lane = t & 63;
    const float sd = sdst[n * HEADS + h];
    const int jbeg = row_ptr[n], jend = row_ptr[n + 1];
    float den = 0.f, acc = 0.f;
    for (int base = jbeg; base < jend; base += 64) {
        int c = jend - base; if (c > 64) c = 64;
        int s = 0; float ex = 0.f;
        if (lane < c) {
            s = csr_src[base + lane];
            float e = ssrc[s * HEADS + h] + sd;
            e = e > 0.f ? e : 0.2f * e;
            ex = __expf(e);
        }
        den += ex;
        int q = 0;
        for (; q + 3 < c; q += 4) {
            int   s0 = __shfl(s, q),     s1 = __shfl(s, q + 1);
            int   s2 = __shfl(s, q + 2), s3 = __shfl(s, q + 3);
            float a0 = __shfl(ex, q),     a1 = __shfl(ex, q + 1);
            float a2 = __shfl(ex, q + 2), a3 = __shfl(ex, q + 3);
            float x0 = __half2float(xp1h[(size_t)s0 * F1 + t]);
            float x1 = __half2float(xp1h[(size_t)s1 * F1 + t]);
            float x2 = __half2float(xp1h[(size_t)s2 * F1 + t]);
            float x3 = __half2float(xp1h[(size_t)s3 * F1 + t]);
            acc = fmaf(a0, x0, acc); acc = fmaf(a1, x1, acc);
            acc = fmaf(a2, x2, acc); acc = fmaf(a3, x3, acc);
        }
        for (; q < c; ++q) {
            int   sq = __shfl(s, q);
            float aq = __shfl(ex, q);
            acc = fmaf(aq, __half2float(xp1h[(size_t)sq * F1 + t]), acc);
        }
    }
#pragma unroll
    for (int off = 32; off; off >>= 1) den += __shfl_xor(den, off);
    float v = acc / (den + 1e-16f) + bias[t];
    hbuf[n * F1 + t] = v > 0.f ? v : 0.f;
}

// ================= Layer 2 GEMM: xp2 = h @ W2 (+fused scores), fp16 out ========
// 16 nodes per block; wave w handles 4 nodes; lane = col
__global__ __launch_bounds__(256) void k_gemm2(
    const float* __restrict__ hbuf, const float* __restrict__ W2,
    const float* __restrict__ as2, const float* __restrict__ ad2,
    __half* __restrict__ xp2h, float* __restrict__ ssrc, float* __restrict__ sdst)
{
    __shared__ float hs[16][F1];
    const int nb = blockIdx.x * 16, t = threadIdx.x;
#pragma unroll
    for (int r = 0; r < 16; ++r) {
        int idx = r * 256 + t;
        hs[idx >> 8][idx & 255] = hbuf[nb * F1 + idx];
    }
    __syncthreads();
    const int w = t >> 6, lane = t & 63;
    float acc[4] = {0.f, 0.f, 0.f, 0.f};
#pragma unroll 2
    for (int k = 0; k < F1; ++k) {
        float wv = W2[k * OUTD + lane];
#pragma unroll
        for (int j = 0; j < 4; ++j) acc[j] = fmaf(hs[w * 4 + j][k], wv, acc[j]);
    }
    const float a_s = as2[lane], a_d = ad2[lane];
#pragma unroll
    for (int j = 0; j < 4; ++j) {
        int n = nb + w * 4 + j;
        xp2h[(size_t)n * OUTD + lane] = __float2half(acc[j]);
        float ps = acc[j] * a_s, pd = acc[j] * a_d;
#pragma unroll
        for (int off = 32; off; off >>= 1) {
            ps += __shfl_down(ps, off);
            pd += __shfl_down(pd, off);
        }
        if (lane == 0) { ssrc[n] = ps; sdst[n] = pd; }
    }
}

// ===== Layer 2 fused softmax+aggregate+bias -> d_out =====
// one wave per node (4 nodes/block); lane = channel; same chunk+shfl scheme
__global__ __launch_bounds__(256) void k_agg2(
    const int* __restrict__ row_ptr, const int* __restrict__ csr_src,
    const float* __restrict__ ssrc, const float* __restrict__ sdst,
    const __half* __restrict__ xp2h, const float* __restrict__ bias,
    float* __restrict__ out)
{
    const int w = threadIdx.x >> 6, lane = threadIdx.x & 63;
    const int n = blockIdx.x * 4 + w;
    const float sd = sdst[n];
    const int jbeg = row_ptr[n], jend = row_ptr[n + 1];
    float den = 0.f, acc = 0.f;
    for (int base = jbeg; base < jend; base += 64) {
        int c = jend - base; if (c > 64) c = 64;
        int s = 0; float ex = 0.f;
        if (lane < c) {
            s = csr_src[base + lane];
            float e = ssrc[s] + sd;
            e = e > 0.f ? e : 0.2f * e;
            ex = __expf(e);
        }
        den += ex;
        int q = 0;
        for (; q + 3 < c; q += 4) {
            int   s0 = __shfl(s, q),     s1 = __shfl(s, q + 1);
            int   s2 = __shfl(s, q + 2), s3 = __shfl(s, q + 3);
            float a0 = __shfl(ex, q),     a1 = __shfl(ex, q + 1);
            float a2 = __shfl(ex, q + 2), a3 = __shfl(ex, q + 3);
            float x0 = __half2float(xp2h[(size_t)s0 * OUTD + lane]);
            float x1 = __half2float(xp2h[(size_t)s1 * OUTD + lane]);
            float x2 = __half2float(xp2h[(size_t)s2 * OUTD + lane]);
            float x3 = __half2float(xp2h[(size_t)s3 * OUTD + lane]);
            acc = fmaf(a0, x0, acc); acc = fmaf(a1, x1, acc);
            acc = fmaf(a2, x2, acc); acc = fmaf(a3, x3, acc);
        }
        for (; q < c; ++q) {
            int   sq = __shfl(s, q);
            float aq = __shfl(ex, q);
            acc = fmaf(aq, __half2float(xp2h[(size_t)sq * OUTD + lane]), acc);
        }
    }
#pragma unroll
    for (int off = 32; off; off >>= 1) den += __shfl_xor(den, off);
    out[n * OUTD + lane] = acc / (den + 1e-16f) + bias[lane];
}

extern "C" void kernel_launch(void* const* d_in, const int* in_sizes, int n_in,
                              void* d_out, int out_size, void* d_ws, size_t ws_size,
                              hipStream_t stream)
{
    (void)in_sizes; (void)n_in; (void)out_size; (void)ws_size;
    const float* x   = (const float*)d_in[0];
    const int*   ei  = (const int*)d_in[1];
    const float* W1  = (const float*)d_in[2];
    const float* as1 = (const float*)d_in[3];
    const float* ad1 = (const float*)d_in[4];
    const float* b1  = (const float*)d_in[5];
    const float* W2  = (const float*)d_in[6];
    const float* as2 = (const float*)d_in[7];
    const float* ad2 = (const float*)d_in[8];
    const float* b2  = (const float*)d_in[9];
    float* out = (float*)d_out;

    // workspace layout (~83 MB)
    __half* xp1h = (__half*)d_ws;                           // N*F1 halves (25.6 MB)
    float* hbuf  = (float*)(xp1h + (size_t)NODES * F1);     // N*F1 f32 (51.2 MB)
    float* ssrc1 = hbuf + (size_t)NODES * F1;               // N*4
    float* sdst1 = ssrc1 + (size_t)NODES * HEADS;           // N*4
    float* ssrc2 = sdst1 + (size_t)NODES * HEADS;           // N
    float* sdst2 = ssrc2 + (size_t)NODES;                   // N
    int* deg     = (int*)(sdst2 + (size_t)NODES);           // N
    int* row_ptr = deg + NODES;                             // N+1
    int* bsum    = row_ptr + NODES + 1;                     // 256
    int* cursor  = bsum + 256;                              // N
    int* csr_src = cursor + NODES;                          // NE2
    __half* xp2h = xp1h;   // alias: xp1h dead after k_agg1

    // ---- CSR build (dst-sorted) ----
    hipMemsetAsync(deg, 0, sizeof(int) * NODES, stream);
    k_hist<<<(NE2 + 255) / 256, 256, 0, stream>>>(ei, deg);
    k_scan1<<<NBLK_SCAN, 256, 0, stream>>>(deg, row_ptr, bsum);
    k_scan2<<<1, 256, 0, stream>>>(bsum);
    k_scan3<<<NBLK_SCAN, 256, 0, stream>>>(row_ptr, bsum, cursor);
    k_scatter<<<(NE2 + 255) / 256, 256, 0, stream>>>(ei, cursor, csr_src);

    // ---- layer 1 ----
    k_gemm1<<<NODES / 8, 256, 0, stream>>>(x, W1, as1, ad1, xp1h, ssrc1, sdst1);
    k_agg1<<<NODES, 256, 0, stream>>>(row_ptr, csr_src, ssrc1, sdst1, xp1h, b1, hbuf);

    // ---- layer 2 ----
    k_gemm2<<<NODES / 16, 256, 0, stream>>>(hbuf, W2, as2, ad2, xp2h, ssrc2, sdst2);
    k_agg2<<<NODES / 4, 256, 0, stream>>>(row_ptr, csr_src, ssrc2, sdst2, xp2h, b2, out);
}

// Round 5
// 434.019 us; speedup vs baseline: 3.5077x; 1.0737x over previous
//
#include <hip/hip_runtime.h>
#include <hip/hip_bf16.h>
#include <hip/hip_fp16.h>

// Problem constants (from reference)
#define NODES 50000
#define NEDGE 800000
#define NE2   850000   // NEDGE + NODES self-loops
#define INDIM 128
#define F1    256      // HEADS*HID
#define HEADS 4
#define HID   64
#define OUTD  64
#define NBLK_SCAN 196  // ceil(NODES/256)

// ================= CSR build =================
__global__ void k_hist(const int* __restrict__ ei, int* __restrict__ deg)
{
    int i = blockIdx.x * 256 + threadIdx.x;
    if (i >= NE2) return;
    int d = (i < NEDGE) ? ei[NEDGE + i] : (i - NEDGE);
    atomicAdd(&deg[d], 1);
}

__global__ void k_scan1(const int* __restrict__ deg, int* __restrict__ excl,
                        int* __restrict__ bsum)
{
    __shared__ int sh[256];
    int t = threadIdx.x;
    int i = blockIdx.x * 256 + t;
    int v = (i < NODES) ? deg[i] : 0;
    sh[t] = v; __syncthreads();
    for (int off = 1; off < 256; off <<= 1) {
        int tv = (t >= off) ? sh[t - off] : 0;
        __syncthreads();
        sh[t] += tv;
        __syncthreads();
    }
    if (i < NODES) excl[i] = sh[t] - v;
    if (t == 255) bsum[blockIdx.x] = sh[255];
}

__global__ void k_scan2(int* __restrict__ bsum)
{
    __shared__ int sh[256];
    int t = threadIdx.x;
    int v = (t < NBLK_SCAN) ? bsum[t] : 0;
    sh[t] = v; __syncthreads();
    for (int off = 1; off < 256; off <<= 1) {
        int tv = (t >= off) ? sh[t - off] : 0;
        __syncthreads();
        sh[t] += tv;
        __syncthreads();
    }
    if (t < NBLK_SCAN) bsum[t] = sh[t] - v;
}

__global__ void k_scan3(int* __restrict__ row_ptr, const int* __restrict__ bsum,
                        int* __restrict__ cursor)
{
    int i = blockIdx.x * 256 + threadIdx.x;
    if (i < NODES) {
        int v = row_ptr[i] + bsum[i >> 8];
        row_ptr[i] = v;
        cursor[i] = v;
    }
    if (i == 0) row_ptr[NODES] = NE2;
}

__global__ void k_scatter(const int* __restrict__ ei, int* __restrict__ cursor,
                          int* __restrict__ csr_src)
{
    int i = blockIdx.x * 256 + threadIdx.x;
    if (i >= NE2) return;
    int s, d;
    if (i < NEDGE) { s = ei[i]; d = ei[NEDGE + i]; } else { s = d = i - NEDGE; }
    int pos = atomicAdd(&cursor[d], 1);
    csr_src[pos] = s;
}

// ================= Layer 1 GEMM: xp1 = x @ W1 (+fused attention scores) ========
// 8 nodes per block; thread t -> out col t; acc[8] in regs; xp1 stored fp16
__global__ __launch_bounds__(256) void k_gemm1(
    const float* __restrict__ x, const float* __restrict__ W1,
    const float* __restrict__ as1, const float* __restrict__ ad1,
    __half* __restrict__ xp1h, float* __restrict__ ssrc, float* __restrict__ sdst)
{
    __shared__ float xs[8][INDIM];
    const int nb = blockIdx.x * 8, t = threadIdx.x;
#pragma unroll
    for (int r = 0; r < 4; ++r) {
        int idx = r * 256 + t;
        xs[idx >> 7][idx & 127] = x[nb * INDIM + idx];
    }
    __syncthreads();
    float acc[8] = {0.f, 0.f, 0.f, 0.f, 0.f, 0.f, 0.f, 0.f};
#pragma unroll 4
    for (int k = 0; k < INDIM; ++k) {
        float wv = W1[k * F1 + t];
#pragma unroll
        for (int r = 0; r < 8; ++r) acc[r] = fmaf(xs[r][k], wv, acc[r]);
    }
    const float a_s = as1[t], a_d = ad1[t];
    const int h = t >> 6, c = t & 63;
#pragma unroll
    for (int r = 0; r < 8; ++r) {
        xp1h[(nb + r) * F1 + t] = __float2half(acc[r]);
        float ps = acc[r] * a_s, pd = acc[r] * a_d;
#pragma unroll
        for (int off = 32; off; off >>= 1) {
            ps += __shfl_down(ps, off);
            pd += __shfl_down(pd, off);
        }
        if (c == 0) {
            ssrc[(nb + r) * HEADS + h] = ps;
            sdst[(nb + r) * HEADS + h] = pd;
        }
    }
}

// ===== Layer 1 fused softmax+aggregate (gather; half2 lanes, shfl-bcast) =====
// 2 nodes per block; node = 2 waves; lane handles channel pair (half2).
// wave-half (32 lanes) <-> one head: lane<32 -> head 2*wp, lane>=32 -> 2*wp+1
__global__ __launch_bounds__(256) void k_agg1(
    const int* __restrict__ row_ptr, const int* __restrict__ csr_src,
    const float* __restrict__ ssrc, const float* __restrict__ sdst,
    const __half2* __restrict__ xp1h2, const float2* __restrict__ bias2,
    float2* __restrict__ hbuf2)
{
    const int t = threadIdx.x;
    const int wv = t >> 6, lane = t & 63;
    const int wp = wv & 1;                    // wave within node pair
    const int n  = blockIdx.x * 2 + (wv >> 1);
    const int h  = wp * 2 + (lane >> 5);      // this lane's head
    const int chp = wp * 64 + lane;           // half2 index within row (0..127)
    const float sd = sdst[n * HEADS + h];
    const int jbeg = row_ptr[n], jend = row_ptr[n + 1];
    const int sel = lane & 32;
    const int le  = lane & 31;

    float den = 0.f, acc0 = 0.f, acc1 = 0.f;
    for (int base = jbeg; base < jend; base += 32) {
        int c = jend - base; if (c > 32) c = 32;
        int s = 0; float ex = 0.f;
        if (le < c) {
            s = csr_src[base + le];
            float e = ssrc[s * HEADS + h] + sd;
            e = e > 0.f ? e : 0.2f * e;
            ex = __expf(e);
        }
        den += ex;   // lane's own head
        int q = 0;
        for (; q + 3 < c; q += 4) {
            int   s0 = __shfl(s, q),     s1 = __shfl(s, q + 1);
            int   s2 = __shfl(s, q + 2), s3 = __shfl(s, q + 3);
            float a0 = __shfl(ex, q | sel),       a1 = __shfl(ex, (q + 1) | sel);
            float a2 = __shfl(ex, (q + 2) | sel), a3 = __shfl(ex, (q + 3) | sel);
            float2 f0 = __half22float2(xp1h2[s0 * 128 + chp]);
            float2 f1 = __half22float2(xp1h2[s1 * 128 + chp]);
            float2 f2 = __half22float2(xp1h2[s2 * 128 + chp]);
            float2 f3 = __half22float2(xp1h2[s3 * 128 + chp]);
            acc0 = fmaf(a0, f0.x, acc0); acc1 = fmaf(a0, f0.y, acc1);
            acc0 = fmaf(a1, f1.x, acc0); acc1 = fmaf(a1, f1.y, acc1);
            acc0 = fmaf(a2, f2.x, acc0); acc1 = fmaf(a2, f2.y, acc1);
            acc0 = fmaf(a3, f3.x, acc0); acc1 = fmaf(a3, f3.y, acc1);
        }
        for (; q < c; ++q) {
            int   sq = __shfl(s, q);
            float aq = __shfl(ex, q | sel);
            float2 fq = __half22float2(xp1h2[sq * 128 + chp]);
            acc0 = fmaf(aq, fq.x, acc0); acc1 = fmaf(aq, fq.y, acc1);
        }
    }
    // per-head denominator: reduce within the 32-lane half only
#pragma unroll
    for (int off = 16; off; off >>= 1) den += __shfl_xor(den, off);
    const float rd = 1.f / (den + 1e-16f);
    float2 b = bias2[chp];
    float v0 = fmaf(acc0, rd, b.x), v1 = fmaf(acc1, rd, b.y);
    float2 o; o.x = v0 > 0.f ? v0 : 0.f; o.y = v1 > 0.f ? v1 : 0.f;
    hbuf2[n * 128 + chp] = o;
}

// ================= Layer 2 GEMM: xp2 = h @ W2 (+fused scores), fp16 out ========
// 16 nodes per block; wave w handles 4 nodes; lane = col
__global__ __launch_bounds__(256) void k_gemm2(
    const float* __restrict__ hbuf, const float* __restrict__ W2,
    const float* __restrict__ as2, const float* __restrict__ ad2,
    __half* __restrict__ xp2h, float* __restrict__ ssrc, float* __restrict__ sdst)
{
    __shared__ float hs[16][F1];
    const int nb = blockIdx.x * 16, t = threadIdx.x;
#pragma unroll
    for (int r = 0; r < 16; ++r) {
        int idx = r * 256 + t;
        hs[idx >> 8][idx & 255] = hbuf[nb * F1 + idx];
    }
    __syncthreads();
    const int w = t >> 6, lane = t & 63;
    float acc[4] = {0.f, 0.f, 0.f, 0.f};
#pragma unroll 2
    for (int k = 0; k < F1; ++k) {
        float wv = W2[k * OUTD + lane];
#pragma unroll
        for (int j = 0; j < 4; ++j) acc[j] = fmaf(hs[w * 4 + j][k], wv, acc[j]);
    }
    const float a_s = as2[lane], a_d = ad2[lane];
#pragma unroll
    for (int j = 0; j < 4; ++j) {
        int n = nb + w * 4 + j;
        xp2h[n * OUTD + lane] = __float2half(acc[j]);
        float ps = acc[j] * a_s, pd = acc[j] * a_d;
#pragma unroll
        for (int off = 32; off; off >>= 1) {
            ps += __shfl_down(ps, off);
            pd += __shfl_down(pd, off);
        }
        if (lane == 0) { ssrc[n] = ps; sdst[n] = pd; }
    }
}

// ===== Layer 2 fused softmax+aggregate+bias -> d_out =====
// one wave per node (4 nodes/block); lane = channel; chunk 64, unroll 8
__global__ __launch_bounds__(256) void k_agg2(
    const int* __restrict__ row_ptr, const int* __restrict__ csr_src,
    const float* __restrict__ ssrc, const float* __restrict__ sdst,
    const __half* __restrict__ xp2h, const float* __restrict__ bias,
    float* __restrict__ out)
{
    const int w = threadIdx.x >> 6, lane = threadIdx.x & 63;
    const int n = blockIdx.x * 4 + w;
    const float sd = sdst[n];
    const int jbeg = row_ptr[n], jend = row_ptr[n + 1];
    float den = 0.f, acc = 0.f;
    for (int base = jbeg; base < jend; base += 64) {
        int c = jend - base; if (c > 64) c = 64;
        int s = 0; float ex = 0.f;
        if (lane < c) {
            s = csr_src[base + lane];
            float e = ssrc[s] + sd;
            e = e > 0.f ? e : 0.2f * e;
            ex = __expf(e);
        }
        den += ex;
        int q = 0;
        for (; q + 7 < c; q += 8) {
            int   s0 = __shfl(s, q),     s1 = __shfl(s, q + 1);
            int   s2 = __shfl(s, q + 2), s3 = __shfl(s, q + 3);
            int   s4 = __shfl(s, q + 4), s5 = __shfl(s, q + 5);
            int   s6 = __shfl(s, q + 6), s7 = __shfl(s, q + 7);
            float a0 = __shfl(ex, q),     a1 = __shfl(ex, q + 1);
            float a2 = __shfl(ex, q + 2), a3 = __shfl(ex, q + 3);
            float a4 = __shfl(ex, q + 4), a5 = __shfl(ex, q + 5);
            float a6 = __shfl(ex, q + 6), a7 = __shfl(ex, q + 7);
            float x0 = __half2float(xp2h[s0 * OUTD + lane]);
            float x1 = __half2float(xp2h[s1 * OUTD + lane]);
            float x2 = __half2float(xp2h[s2 * OUTD + lane]);
            float x3 = __half2float(xp2h[s3 * OUTD + lane]);
            float x4 = __half2float(xp2h[s4 * OUTD + lane]);
            float x5 = __half2float(xp2h[s5 * OUTD + lane]);
            float x6 = __half2float(xp2h[s6 * OUTD + lane]);
            float x7 = __half2float(xp2h[s7 * OUTD + lane]);
            acc = fmaf(a0, x0, acc); acc = fmaf(a1, x1, acc);
            acc = fmaf(a2, x2, acc); acc = fmaf(a3, x3, acc);
            acc = fmaf(a4, x4, acc); acc = fmaf(a5, x5, acc);
            acc = fmaf(a6, x6, acc); acc = fmaf(a7, x7, acc);
        }
        for (; q < c; ++q) {
            int   sq = __shfl(s, q);
            float aq = __shfl(ex, q);
            acc = fmaf(aq, __half2float(xp2h[sq * OUTD + lane]), acc);
        }
    }
#pragma unroll
    for (int off = 32; off; off >>= 1) den += __shfl_xor(den, off);
    out[n * OUTD + lane] = acc / (den + 1e-16f) + bias[lane];
}

extern "C" void kernel_launch(void* const* d_in, const int* in_sizes, int n_in,
                              void* d_out, int out_size, void* d_ws, size_t ws_size,
                              hipStream_t stream)
{
    (void)in_sizes; (void)n_in; (void)out_size; (void)ws_size;
    const float* x   = (const float*)d_in[0];
    const int*   ei  = (const int*)d_in[1];
    const float* W1  = (const float*)d_in[2];
    const float* as1 = (const float*)d_in[3];
    const float* ad1 = (const float*)d_in[4];
    const float* b1  = (const float*)d_in[5];
    const float* W2  = (const float*)d_in[6];
    const float* as2 = (const float*)d_in[7];
    const float* ad2 = (const float*)d_in[8];
    const float* b2  = (const float*)d_in[9];
    float* out = (float*)d_out;

    // workspace layout (~83 MB)
    __half* xp1h = (__half*)d_ws;                           // N*F1 halves (25.6 MB)
    float* hbuf  = (float*)(xp1h + (size_t)NODES * F1);     // N*F1 f32 (51.2 MB)
    float* ssrc1 = hbuf + (size_t)NODES * F1;               // N*4
    float* sdst1 = ssrc1 + (size_t)NODES * HEADS;           // N*4
    float* ssrc2 = sdst1 + (size_t)NODES * HEADS;           // N
    float* sdst2 = ssrc2 + (size_t)NODES;                   // N
    int* deg     = (int*)(sdst2 + (size_t)NODES);           // N
    int* row_ptr = deg + NODES;                             // N+1
    int* bsum    = row_ptr + NODES + 1;                     // 256
    int* cursor  = bsum + 256;                              // N
    int* csr_src = cursor + NODES;                          // NE2
    __half* xp2h = xp1h;   // alias: xp1h dead after k_agg1

    // ---- CSR build (dst-sorted) ----
    hipMemsetAsync(deg, 0, sizeof(int) * NODES, stream);
    k_hist<<<(NE2 + 255) / 256, 256, 0, stream>>>(ei, deg);
    k_scan1<<<NBLK_SCAN, 256, 0, stream>>>(deg, row_ptr, bsum);
    k_scan2<<<1, 256, 0, stream>>>(bsum);
    k_scan3<<<NBLK_SCAN, 256, 0, stream>>>(row_ptr, bsum, cursor);
    k_scatter<<<(NE2 + 255) / 256, 256, 0, stream>>>(ei, cursor, csr_src);

    // ---- layer 1 ----
    k_gemm1<<<NODES / 8, 256, 0, stream>>>(x, W1, as1, ad1, xp1h, ssrc1, sdst1);
    k_agg1<<<NODES / 2, 256, 0, stream>>>(row_ptr, csr_src, ssrc1, sdst1,
                                          (const __half2*)xp1h, (const float2*)b1,
                                          (float2*)hbuf);

    // ---- layer 2 ----
    k_gemm2<<<NODES / 16, 256, 0, stream>>>(hbuf, W2, as2, ad2, xp2h, ssrc2, sdst2);
    k_agg2<<<NODES / 4, 256, 0, stream>>>(row_ptr, csr_src, ssrc2, sdst2, xp2h, b2, out);
}

// Round 6
// 341.060 us; speedup vs baseline: 4.4638x; 1.2726x over previous
//
#include <hip/hip_runtime.h>
#include <hip/hip_bf16.h>
#include <hip/hip_fp16.h>

// Problem constants (from reference)
#define NODES 50000
#define NEDGE 800000
#define NE2   850000   // NEDGE + NODES self-loops
#define INDIM 128
#define F1    256      // HEADS*HID
#define HEADS 4
#define HID   64
#define OUTD  64
#define NBLK_SCAN 196  // ceil(NODES/256)
#define MTILES 3125    // NODES/16

typedef _Float16 f16;
typedef _Float16 f16x8 __attribute__((ext_vector_type(8)));
typedef float    f32x4 __attribute__((ext_vector_type(4)));

// ================= CSR build =================
__global__ void k_hist(const int* __restrict__ ei, int* __restrict__ deg)
{
    int i = blockIdx.x * 256 + threadIdx.x;
    if (i >= NE2) return;
    int d = (i < NEDGE) ? ei[NEDGE + i] : (i - NEDGE);
    atomicAdd(&deg[d], 1);
}

__global__ void k_scan1(const int* __restrict__ deg, int* __restrict__ excl,
                        int* __restrict__ bsum)
{
    __shared__ int sh[256];
    int t = threadIdx.x;
    int i = blockIdx.x * 256 + t;
    int v = (i < NODES) ? deg[i] : 0;
    sh[t] = v; __syncthreads();
    for (int off = 1; off < 256; off <<= 1) {
        int tv = (t >= off) ? sh[t - off] : 0;
        __syncthreads();
        sh[t] += tv;
        __syncthreads();
    }
    if (i < NODES) excl[i] = sh[t] - v;
    if (t == 255) bsum[blockIdx.x] = sh[255];
}

__global__ void k_scan2(int* __restrict__ bsum)
{
    __shared__ int sh[256];
    int t = threadIdx.x;
    int v = (t < NBLK_SCAN) ? bsum[t] : 0;
    sh[t] = v; __syncthreads();
    for (int off = 1; off < 256; off <<= 1) {
        int tv = (t >= off) ? sh[t - off] : 0;
        __syncthreads();
        sh[t] += tv;
        __syncthreads();
    }
    if (t < NBLK_SCAN) bsum[t] = sh[t] - v;
}

__global__ void k_scan3(int* __restrict__ row_ptr, const int* __restrict__ bsum,
                        int* __restrict__ cursor)
{
    int i = blockIdx.x * 256 + threadIdx.x;
    if (i < NODES) {
        int v = row_ptr[i] + bsum[i >> 8];
        row_ptr[i] = v;
        cursor[i] = v;
    }
    if (i == 0) row_ptr[NODES] = NE2;
}

__global__ void k_scatter(const int* __restrict__ ei, int* __restrict__ cursor,
                          int* __restrict__ csr_src)
{
    int i = blockIdx.x * 256 + threadIdx.x;
    if (i >= NE2) return;
    int s, d;
    if (i < NEDGE) { s = ei[i]; d = ei[NEDGE + i]; } else { s = d = i - NEDGE; }
    int pos = atomicAdd(&cursor[d], 1);
    csr_src[pos] = s;
}

// ================= W pre-swizzle into MFMA B-fragment order ===============
// frag (ct,kb): lane l holds W[k = kb*32 + (l>>4)*8 + j][col = ct*16 + (l&15)]
// W1p[((ct*4+kb)*64 + l)*8 + j]  (32768 f16)
__global__ void k_prepW1(const float* __restrict__ W1, f16* __restrict__ W1p)
{
    int idx = blockIdx.x * 256 + threadIdx.x;   // < 32768
    int j = idx & 7, l = (idx >> 3) & 63, fi = idx >> 9;
    int kb = fi & 3, ct = fi >> 2;
    int k = kb * 32 + (l >> 4) * 8 + j;
    int col = ct * 16 + (l & 15);
    W1p[idx] = (f16)W1[k * F1 + col];
}

// W2p[((ct*8+kb)*64 + l)*8 + j]  (16384 f16)
__global__ void k_prepW2(const float* __restrict__ W2, f16* __restrict__ W2p)
{
    int idx = blockIdx.x * 256 + threadIdx.x;   // < 16384
    int j = idx & 7, l = (idx >> 3) & 63, fi = idx >> 9;
    int kb = fi & 7, ct = fi >> 3;
    int k = kb * 32 + (l >> 4) * 8 + j;
    int col = ct * 16 + (l & 15);
    W2p[idx] = (f16)W2[k * OUTD + col];
}

// ================= Layer 1 GEMM (MFMA): xp1h = f16(x @ W1) =================
// wave = 16 rows x 256 cols; 4 waves/block; A from f32 x (inline cvt)
__global__ __launch_bounds__(256) void k_gemm1m(
    const float* __restrict__ x, const f16* __restrict__ W1p,
    f16* __restrict__ xp1h)
{
    const int wv = threadIdx.x >> 6, lane = threadIdx.x & 63;
    const int l15 = lane & 15, quad = lane >> 4;
    const int rowtile = blockIdx.x * 4 + wv;
    if (rowtile >= MTILES) return;
    const int rowbase = rowtile * 16;

    // A fragments: A[m=l15][k = kb*32 + quad*8 + j]
    f16x8 afrag[4];
    const float* xrow = x + (rowbase + l15) * INDIM + quad * 8;
#pragma unroll
    for (int kb = 0; kb < 4; ++kb) {
        float4 u0 = *(const float4*)(xrow + kb * 32);
        float4 u1 = *(const float4*)(xrow + kb * 32 + 4);
        f16x8 a;
        a[0] = (f16)u0.x; a[1] = (f16)u0.y; a[2] = (f16)u0.z; a[3] = (f16)u0.w;
        a[4] = (f16)u1.x; a[5] = (f16)u1.y; a[6] = (f16)u1.z; a[7] = (f16)u1.w;
        afrag[kb] = a;
    }

    const f16x8* Wf = (const f16x8*)W1p;
    f32x4 acc[16];
#pragma unroll
    for (int ct = 0; ct < 16; ++ct) acc[ct] = (f32x4){0.f, 0.f, 0.f, 0.f};
#pragma unroll
    for (int ct = 0; ct < 16; ++ct) {
#pragma unroll
        for (int kb = 0; kb < 4; ++kb) {
            f16x8 b = Wf[(ct * 4 + kb) * 64 + lane];
            acc[ct] = __builtin_amdgcn_mfma_f32_16x16x32_f16(afrag[kb], b, acc[ct], 0, 0, 0);
        }
    }
    // C/D: col = ct*16 + l15, row = quad*4 + r
    const int orow = rowbase + quad * 4;
#pragma unroll
    for (int ct = 0; ct < 16; ++ct) {
#pragma unroll
        for (int r = 0; r < 4; ++r)
            xp1h[(orow + r) * F1 + ct * 16 + l15] = (f16)acc[ct][r];
    }
}

// ================= Layer 1 scores from xp1h =================
// 4 nodes/block (wave each); lane covers ch {2l,2l+1} and {128+2l,128+2l+1}
__global__ __launch_bounds__(256) void k_score1(
    const f16* __restrict__ xp1h, const float* __restrict__ as1,
    const float* __restrict__ ad1, float* __restrict__ ssrc,
    float* __restrict__ sdst)
{
    const int wv = threadIdx.x >> 6, lane = threadIdx.x & 63;
    const int n = blockIdx.x * 4 + wv;
    const __half2* xr = (const __half2*)(xp1h + n * F1);
    float2 f0 = __half22float2(xr[lane]);
    float2 f1 = __half22float2(xr[64 + lane]);
    const float2* sa = (const float2*)as1;
    const float2* da = (const float2*)ad1;
    float2 a0 = sa[lane], a1 = sa[64 + lane];
    float2 d0 = da[lane], d1 = da[64 + lane];
    float p0 = f0.x * a0.x + f0.y * a0.y;   // head lane>>5
    float p1 = f1.x * a1.x + f1.y * a1.y;   // head 2 + (lane>>5)
    float q0 = f0.x * d0.x + f0.y * d0.y;
    float q1 = f1.x * d1.x + f1.y * d1.y;
#pragma unroll
    for (int off = 16; off; off >>= 1) {
        p0 += __shfl_xor(p0, off); p1 += __shfl_xor(p1, off);
        q0 += __shfl_xor(q0, off); q1 += __shfl_xor(q1, off);
    }
    if ((lane & 31) == 0) {
        int h0 = lane >> 5;
        ssrc[n * HEADS + h0] = p0;  ssrc[n * HEADS + h0 + 2] = p1;
        sdst[n * HEADS + h0] = q0;  sdst[n * HEADS + h0 + 2] = q1;
    }
}

// ===== Layer 1 fused softmax+aggregate (gather; half2 lanes, shfl-bcast) =====
// 2 nodes per block; node = 2 waves; lane handles channel pair (half2) -> f16 out
__global__ __launch_bounds__(256) void k_agg1(
    const int* __restrict__ row_ptr, const int* __restrict__ csr_src,
    const float* __restrict__ ssrc, const float* __restrict__ sdst,
    const __half2* __restrict__ xp1h2, const float2* __restrict__ bias2,
    __half2* __restrict__ hbuf2)
{
    const int t = threadIdx.x;
    const int wv = t >> 6, lane = t & 63;
    const int wp = wv & 1;                    // wave within node pair
    const int n  = blockIdx.x * 2 + (wv >> 1);
    const int h  = wp * 2 + (lane >> 5);      // this lane's head
    const int chp = wp * 64 + lane;           // half2 index within row (0..127)
    const float sd = sdst[n * HEADS + h];
    const int jbeg = row_ptr[n], jend = row_ptr[n + 1];
    const int sel = lane & 32;
    const int le  = lane & 31;

    float den = 0.f, acc0 = 0.f, acc1 = 0.f;
    for (int base = jbeg; base < jend; base += 32) {
        int c = jend - base; if (c > 32) c = 32;
        int s = 0; float ex = 0.f;
        if (le < c) {
            s = csr_src[base + le];
            float e = ssrc[s * HEADS + h] + sd;
            e = e > 0.f ? e : 0.2f * e;
            ex = __expf(e);
        }
        den += ex;   // lane's own head
        int q = 0;
        for (; q + 3 < c; q += 4) {
            int   s0 = __shfl(s, q),     s1 = __shfl(s, q + 1);
            int   s2 = __shfl(s, q + 2), s3 = __shfl(s, q + 3);
            float a0 = __shfl(ex, q | sel),       a1 = __shfl(ex, (q + 1) | sel);
            float a2 = __shfl(ex, (q + 2) | sel), a3 = __shfl(ex, (q + 3) | sel);
            float2 f0 = __half22float2(xp1h2[s0 * 128 + chp]);
            float2 f1 = __half22float2(xp1h2[s1 * 128 + chp]);
            float2 f2 = __half22float2(xp1h2[s2 * 128 + chp]);
            float2 f3 = __half22float2(xp1h2[s3 * 128 + chp]);
            acc0 = fmaf(a0, f0.x, acc0); acc1 = fmaf(a0, f0.y, acc1);
            acc0 = fmaf(a1, f1.x, acc0); acc1 = fmaf(a1, f1.y, acc1);
            acc0 = fmaf(a2, f2.x, acc0); acc1 = fmaf(a2, f2.y, acc1);
            acc0 = fmaf(a3, f3.x, acc0); acc1 = fmaf(a3, f3.y, acc1);
        }
        for (; q < c; ++q) {
            int   sq = __shfl(s, q);
            float aq = __shfl(ex, q | sel);
            float2 fq = __half22float2(xp1h2[sq * 128 + chp]);
            acc0 = fmaf(aq, fq.x, acc0); acc1 = fmaf(aq, fq.y, acc1);
        }
    }
#pragma unroll
    for (int off = 16; off; off >>= 1) den += __shfl_xor(den, off);
    const float rd = 1.f / (den + 1e-16f);
    float2 b = bias2[chp];
    float v0 = fmaf(acc0, rd, b.x), v1 = fmaf(acc1, rd, b.y);
    float2 o; o.x = v0 > 0.f ? v0 : 0.f; o.y = v1 > 0.f ? v1 : 0.f;
    hbuf2[n * 128 + chp] = __float22half2_rn(o);
}

// ================= Layer 2 GEMM (MFMA): xp2h = f16(h @ W2) =================
// wave = 16 rows x 64 cols; hbuf is f16 so A-frag is one b128 load
__global__ __launch_bounds__(256) void k_gemm2m(
    const f16* __restrict__ hbuf, const f16* __restrict__ W2p,
    f16* __restrict__ xp2h)
{
    const int wv = threadIdx.x >> 6, lane = threadIdx.x & 63;
    const int l15 = lane & 15, quad = lane >> 4;
    const int rowtile = blockIdx.x * 4 + wv;
    if (rowtile >= MTILES) return;
    const int rowbase = rowtile * 16;

    const f16x8* Wf = (const f16x8*)W2p;
    f32x4 acc[4];
#pragma unroll
    for (int ct = 0; ct < 4; ++ct) acc[ct] = (f32x4){0.f, 0.f, 0.f, 0.f};
    const f16* hrow = hbuf + (rowbase + l15) * F1 + quad * 8;
#pragma unroll
    for (int kb = 0; kb < 8; ++kb) {
        f16x8 a = *(const f16x8*)(hrow + kb * 32);
#pragma unroll
        for (int ct = 0; ct < 4; ++ct) {
            f16x8 b = Wf[(ct * 8 + kb) * 64 + lane];
            acc[ct] = __builtin_amdgcn_mfma_f32_16x16x32_f16(a, b, acc[ct], 0, 0, 0);
        }
    }
    const int orow = rowbase + quad * 4;
#pragma unroll
    for (int ct = 0; ct < 4; ++ct) {
#pragma unroll
        for (int r = 0; r < 4; ++r)
            xp2h[(orow + r) * OUTD + ct * 16 + l15] = (f16)acc[ct][r];
    }
}

// ================= Layer 2 scores from xp2h =================
__global__ __launch_bounds__(256) void k_score2(
    const f16* __restrict__ xp2h, const float* __restrict__ as2,
    const float* __restrict__ ad2, float* __restrict__ ssrc,
    float* __restrict__ sdst)
{
    const int wv = threadIdx.x >> 6, lane = threadIdx.x & 63;
    const int n = blockIdx.x * 4 + wv;
    float v = (float)xp2h[n * OUTD + lane];
    float p = v * as2[lane];
    float q = v * ad2[lane];
#pragma unroll
    for (int off = 32; off; off >>= 1) {
        p += __shfl_xor(p, off);
        q += __shfl_xor(q, off);
    }
    if (lane == 0) { ssrc[n] = p; sdst[n] = q; }
}

// ===== Layer 2 fused softmax+aggregate+bias -> d_out =====
// one wave per node (4 nodes/block); lane = channel; chunk 64, unroll 8
__global__ __launch_bounds__(256) void k_agg2(
    const int* __restrict__ row_ptr, const int* __restrict__ csr_src,
    const float* __restrict__ ssrc, const float* __restrict__ sdst,
    const __half* __restrict__ xp2h, const float* __restrict__ bias,
    float* __restrict__ out)
{
    const int w = threadIdx.x >> 6, lane = threadIdx.x & 63;
    const int n = blockIdx.x * 4 + w;
    const float sd = sdst[n];
    const int jbeg = row_ptr[n], jend = row_ptr[n + 1];
    float den = 0.f, acc = 0.f;
    for (int base = jbeg; base < jend; base += 64) {
        int c = jend - base; if (c > 64) c = 64;
        int s = 0; float ex = 0.f;
        if (lane < c) {
            s = csr_src[base + lane];
            float e = ssrc[s] + sd;
            e = e > 0.f ? e : 0.2f * e;
            ex = __expf(e);
        }
        den += ex;
        int q = 0;
        for (; q + 7 < c; q += 8) {
            int   s0 = __shfl(s, q),     s1 = __shfl(s, q + 1);
            int   s2 = __shfl(s, q + 2), s3 = __shfl(s, q + 3);
            int   s4 = __shfl(s, q + 4), s5 = __shfl(s, q + 5);
            int   s6 = __shfl(s, q + 6), s7 = __shfl(s, q + 7);
            float a0 = __shfl(ex, q),     a1 = __shfl(ex, q + 1);
            float a2 = __shfl(ex, q + 2), a3 = __shfl(ex, q + 3);
            float a4 = __shfl(ex, q + 4), a5 = __shfl(ex, q + 5);
            float a6 = __shfl(ex, q + 6), a7 = __shfl(ex, q + 7);
            float x0 = __half2float(xp2h[s0 * OUTD + lane]);
            float x1 = __half2float(xp2h[s1 * OUTD + lane]);
            float x2 = __half2float(xp2h[s2 * OUTD + lane]);
            float x3 = __half2float(xp2h[s3 * OUTD + lane]);
            float x4 = __half2float(xp2h[s4 * OUTD + lane]);
            float x5 = __half2float(xp2h[s5 * OUTD + lane]);
            float x6 = __half2float(xp2h[s6 * OUTD + lane]);
            float x7 = __half2float(xp2h[s7 * OUTD + lane]);
            acc = fmaf(a0, x0, acc); acc = fmaf(a1, x1, acc);
            acc = fmaf(a2, x2, acc); acc = fmaf(a3, x3, acc);
            acc = fmaf(a4, x4, acc); acc = fmaf(a5, x5, acc);
            acc = fmaf(a6, x6, acc); acc = fmaf(a7, x7, acc);
        }
        for (; q < c; ++q) {
            int   sq = __shfl(s, q);
            float aq = __shfl(ex, q);
            acc = fmaf(aq, __half2float(xp2h[sq * OUTD + lane]), acc);
        }
    }
#pragma unroll
    for (int off = 32; off; off >>= 1) den += __shfl_xor(den, off);
    out[n * OUTD + lane] = acc / (den + 1e-16f) + bias[lane];
}

extern "C" void kernel_launch(void* const* d_in, const int* in_sizes, int n_in,
                              void* d_out, int out_size, void* d_ws, size_t ws_size,
                              hipStream_t stream)
{
    (void)in_sizes; (void)n_in; (void)out_size; (void)ws_size;
    const float* x   = (const float*)d_in[0];
    const int*   ei  = (const int*)d_in[1];
    const float* W1  = (const float*)d_in[2];
    const float* as1 = (const float*)d_in[3];
    const float* ad1 = (const float*)d_in[4];
    const float* b1  = (const float*)d_in[5];
    const float* W2  = (const float*)d_in[6];
    const float* as2 = (const float*)d_in[7];
    const float* ad2 = (const float*)d_in[8];
    const float* b2  = (const float*)d_in[9];
    float* out = (float*)d_out;

    // workspace layout (~58 MB)
    f16* xp1h   = (f16*)d_ws;                              // N*256 f16 (25.6 MB)
    f16* hbuf   = xp1h + (size_t)NODES * F1;               // N*256 f16 (25.6 MB)
    f16* W1p    = hbuf + (size_t)NODES * F1;               // 32768 f16
    f16* W2p    = W1p + 32768;                             // 16384 f16
    float* ssrc1 = (float*)(W2p + 16384);                  // N*4
    float* sdst1 = ssrc1 + (size_t)NODES * HEADS;          // N*4
    float* ssrc2 = sdst1 + (size_t)NODES * HEADS;          // N
    float* sdst2 = ssrc2 + (size_t)NODES;                  // N
    int* deg     = (int*)(sdst2 + (size_t)NODES);          // N
    int* row_ptr = deg + NODES;                            // N+1
    int* bsum    = row_ptr + NODES + 1;                    // 256
    int* cursor  = bsum + 256;                             // N
    int* csr_src = cursor + NODES;                         // NE2
    f16* xp2h    = xp1h;   // alias: xp1h dead after k_agg1

    // ---- CSR build (dst-sorted) + W pre-swizzle ----
    hipMemsetAsync(deg, 0, sizeof(int) * NODES, stream);
    k_hist<<<(NE2 + 255) / 256, 256, 0, stream>>>(ei, deg);
    k_prepW1<<<128, 256, 0, stream>>>(W1, W1p);
    k_prepW2<<<64, 256, 0, stream>>>(W2, W2p);
    k_scan1<<<NBLK_SCAN, 256, 0, stream>>>(deg, row_ptr, bsum);
    k_scan2<<<1, 256, 0, stream>>>(bsum);
    k_scan3<<<NBLK_SCAN, 256, 0, stream>>>(row_ptr, bsum, cursor);
    k_scatter<<<(NE2 + 255) / 256, 256, 0, stream>>>(ei, cursor, csr_src);

    // ---- layer 1 ----
    k_gemm1m<<<(MTILES + 3) / 4, 256, 0, stream>>>(x, W1p, xp1h);
    k_score1<<<NODES / 4, 256, 0, stream>>>(xp1h, as1, ad1, ssrc1, sdst1);
    k_agg1<<<NODES / 2, 256, 0, stream>>>(row_ptr, csr_src, ssrc1, sdst1,
                                          (const __half2*)xp1h, (const float2*)b1,
                                          (__half2*)hbuf);

    // ---- layer 2 ----
    k_gemm2m<<<(MTILES + 3) / 4, 256, 0, stream>>>(hbuf, W2p, xp2h);
    k_score2<<<NODES / 4, 256, 0, stream>>>(xp2h, as2, ad2, ssrc2, sdst2);
    k_agg2<<<NODES / 4, 256, 0, stream>>>(row_ptr, csr_src, ssrc2, sdst2,
                                          (const __half*)xp2h, b2, out);
}

// Round 7
// 330.755 us; speedup vs baseline: 4.6029x; 1.0312x over previous
//
#include <hip/hip_runtime.h>
#include <hip/hip_bf16.h>
#include <hip/hip_fp16.h>

// Problem constants (from reference)
#define NODES 50000
#define NEDGE 800000
#define NE2   850000   // NEDGE + NODES self-loops
#define INDIM 128
#define F1    256      // HEADS*HID
#define HEADS 4
#define HID   64
#define OUTD  64
#define NBLK_SCAN 196  // ceil(NODES/256)
#define MTILES 3125    // NODES/16

typedef _Float16 f16;
typedef _Float16 f16x8 __attribute__((ext_vector_type(8)));
typedef float    f32x4 __attribute__((ext_vector_type(4)));

// ================= CSR build =================
__global__ void k_hist(const int* __restrict__ ei, int* __restrict__ deg)
{
    int i = blockIdx.x * 256 + threadIdx.x;
    if (i >= NE2) return;
    int d = (i < NEDGE) ? ei[NEDGE + i] : (i - NEDGE);
    atomicAdd(&deg[d], 1);
}

__global__ void k_scan1(const int* __restrict__ deg, int* __restrict__ excl,
                        int* __restrict__ bsum)
{
    __shared__ int sh[256];
    int t = threadIdx.x;
    int i = blockIdx.x * 256 + t;
    int v = (i < NODES) ? deg[i] : 0;
    sh[t] = v; __syncthreads();
    for (int off = 1; off < 256; off <<= 1) {
        int tv = (t >= off) ? sh[t - off] : 0;
        __syncthreads();
        sh[t] += tv;
        __syncthreads();
    }
    if (i < NODES) excl[i] = sh[t] - v;
    if (t == 255) bsum[blockIdx.x] = sh[255];
}

__global__ void k_scan2(int* __restrict__ bsum)
{
    __shared__ int sh[256];
    int t = threadIdx.x;
    int v = (t < NBLK_SCAN) ? bsum[t] : 0;
    sh[t] = v; __syncthreads();
    for (int off = 1; off < 256; off <<= 1) {
        int tv = (t >= off) ? sh[t - off] : 0;
        __syncthreads();
        sh[t] += tv;
        __syncthreads();
    }
    if (t < NBLK_SCAN) bsum[t] = sh[t] - v;
}

__global__ void k_scan3(int* __restrict__ row_ptr, const int* __restrict__ bsum,
                        int* __restrict__ cursor)
{
    int i = blockIdx.x * 256 + threadIdx.x;
    if (i < NODES) {
        int v = row_ptr[i] + bsum[i >> 8];
        row_ptr[i] = v;
        cursor[i] = v;
    }
    if (i == 0) row_ptr[NODES] = NE2;
}

__global__ void k_scatter(const int* __restrict__ ei, int* __restrict__ cursor,
                          int* __restrict__ csr_src)
{
    int i = blockIdx.x * 256 + threadIdx.x;
    if (i >= NE2) return;
    int s, d;
    if (i < NEDGE) { s = ei[i]; d = ei[NEDGE + i]; } else { s = d = i - NEDGE; }
    int pos = atomicAdd(&cursor[d], 1);
    csr_src[pos] = s;
}

// ================= W pre-swizzle into MFMA B-fragment order ===============
__global__ void k_prepW1(const float* __restrict__ W1, f16* __restrict__ W1p)
{
    int idx = blockIdx.x * 256 + threadIdx.x;   // < 32768
    int j = idx & 7, l = (idx >> 3) & 63, fi = idx >> 9;
    int kb = fi & 3, ct = fi >> 2;
    int k = kb * 32 + (l >> 4) * 8 + j;
    int col = ct * 16 + (l & 15);
    W1p[idx] = (f16)W1[k * F1 + col];
}

__global__ void k_prepW2(const float* __restrict__ W2, f16* __restrict__ W2p)
{
    int idx = blockIdx.x * 256 + threadIdx.x;   // < 16384
    int j = idx & 7, l = (idx >> 3) & 63, fi = idx >> 9;
    int kb = fi & 7, ct = fi >> 3;
    int k = kb * 32 + (l >> 4) * 8 + j;
    int col = ct * 16 + (l & 15);
    W2p[idx] = (f16)W2[k * OUTD + col];
}

// ================= Layer 1 GEMM (MFMA): xp1h = f16(x @ W1) =================
__global__ __launch_bounds__(256) void k_gemm1m(
    const float* __restrict__ x, const f16* __restrict__ W1p,
    f16* __restrict__ xp1h)
{
    const int wv = threadIdx.x >> 6, lane = threadIdx.x & 63;
    const int l15 = lane & 15, quad = lane >> 4;
    const int rowtile = blockIdx.x * 4 + wv;
    if (rowtile >= MTILES) return;
    const int rowbase = rowtile * 16;

    f16x8 afrag[4];
    const float* xrow = x + (rowbase + l15) * INDIM + quad * 8;
#pragma unroll
    for (int kb = 0; kb < 4; ++kb) {
        float4 u0 = *(const float4*)(xrow + kb * 32);
        float4 u1 = *(const float4*)(xrow + kb * 32 + 4);
        f16x8 a;
        a[0] = (f16)u0.x; a[1] = (f16)u0.y; a[2] = (f16)u0.z; a[3] = (f16)u0.w;
        a[4] = (f16)u1.x; a[5] = (f16)u1.y; a[6] = (f16)u1.z; a[7] = (f16)u1.w;
        afrag[kb] = a;
    }

    const f16x8* Wf = (const f16x8*)W1p;
    f32x4 acc[16];
#pragma unroll
    for (int ct = 0; ct < 16; ++ct) acc[ct] = (f32x4){0.f, 0.f, 0.f, 0.f};
#pragma unroll
    for (int ct = 0; ct < 16; ++ct) {
#pragma unroll
        for (int kb = 0; kb < 4; ++kb) {
            f16x8 b = Wf[(ct * 4 + kb) * 64 + lane];
            acc[ct] = __builtin_amdgcn_mfma_f32_16x16x32_f16(afrag[kb], b, acc[ct], 0, 0, 0);
        }
    }
    const int orow = rowbase + quad * 4;
#pragma unroll
    for (int ct = 0; ct < 16; ++ct) {
#pragma unroll
        for (int r = 0; r < 4; ++r)
            xp1h[(orow + r) * F1 + ct * 16 + l15] = (f16)acc[ct][r];
    }
}

// ================= Layer 1 scores from xp1h =================
__global__ __launch_bounds__(256) void k_score1(
    const f16* __restrict__ xp1h, const float* __restrict__ as1,
    const float* __restrict__ ad1, float* __restrict__ ssrc,
    float* __restrict__ sdst)
{
    const int wv = threadIdx.x >> 6, lane = threadIdx.x & 63;
    const int n = blockIdx.x * 4 + wv;
    const __half2* xr = (const __half2*)(xp1h + n * F1);
    float2 f0 = __half22float2(xr[lane]);
    float2 f1 = __half22float2(xr[64 + lane]);
    const float2* sa = (const float2*)as1;
    const float2* da = (const float2*)ad1;
    float2 a0 = sa[lane], a1 = sa[64 + lane];
    float2 d0 = da[lane], d1 = da[64 + lane];
    float p0 = f0.x * a0.x + f0.y * a0.y;
    float p1 = f1.x * a1.x + f1.y * a1.y;
    float q0 = f0.x * d0.x + f0.y * d0.y;
    float q1 = f1.x * d1.x + f1.y * d1.y;
#pragma unroll
    for (int off = 16; off; off >>= 1) {
        p0 += __shfl_xor(p0, off); p1 += __shfl_xor(p1, off);
        q0 += __shfl_xor(q0, off); q1 += __shfl_xor(q1, off);
    }
    if ((lane & 31) == 0) {
        int h0 = lane >> 5;
        ssrc[n * HEADS + h0] = p0;  ssrc[n * HEADS + h0 + 2] = p1;
        sdst[n * HEADS + h0] = q0;  sdst[n * HEADS + h0 + 2] = q1;
    }
}

// ===== Layer 1 fused softmax+aggregate: ONE wave per node, b128 gather =====
// chunk = 16 edges. Phase A: lane (eq=l&15, ph=l>>4) computes exp(edge,head).
// Phase B: per edge pair, half-wave (32 lanes x 16B) loads full 512B row.
// lane accumulates 8 channels: ch = (l&31)*8 + j; channel head hh=(l&31)>>3.
__global__ __launch_bounds__(256) void k_agg1(
    const int* __restrict__ row_ptr, const int* __restrict__ csr_src,
    const float* __restrict__ ssrc, const float* __restrict__ sdst,
    const f16* __restrict__ xp1h, const float* __restrict__ bias,
    f16* __restrict__ hbuf)
{
    const int wv = threadIdx.x >> 6, l = threadIdx.x & 63;
    const int n = blockIdx.x * 4 + wv;
    const int eq = l & 15, ph = l >> 4;        // phase-A role
    const int hl = l & 31;                     // half-lane: channel chunk
    const int half = l >> 5;                   // edge parity in phase B
    const int exsel = ((hl >> 3) << 4);        // channel-head -> exp lane block
    const float sd = sdst[n * HEADS + ph];
    const int jbeg = row_ptr[n], jend = row_ptr[n + 1];
    const f16x8* xv = (const f16x8*)xp1h;

    float den = 0.f;
    float acc[8] = {0.f,0.f,0.f,0.f,0.f,0.f,0.f,0.f};
    for (int base = jbeg; base < jend; base += 16) {
        int c = jend - base; if (c > 16) c = 16;
        int s = 0; float ex = 0.f;
        if (eq < c) {
            s = csr_src[base + eq];
            float e = ssrc[s * HEADS + ph] + sd;
            e = e > 0.f ? e : 0.2f * e;
            ex = __expf(e);
        }
        den += ex;
        for (int p = 0; 2 * p < c; ++p) {
            int eidx = 2 * p + half;
            int   se = __shfl(s, eidx);
            float ae = __shfl(ex, eidx + exsel);
            f16x8 v = xv[se * 32 + hl];
#pragma unroll
            for (int j = 0; j < 8; ++j) acc[j] = fmaf(ae, (float)v[j], acc[j]);
        }
    }
    // denominator: sum within each 16-lane head group, then pick channel-head's
#pragma unroll
    for (int off = 8; off; off >>= 1) den += __shfl_xor(den, off);
    float dh = __shfl(den, exsel);   // lane exsel = hh*16 holds head hh total
    const float rd = 1.f / (dh + 1e-16f);
    // combine edge-parity halves
#pragma unroll
    for (int j = 0; j < 8; ++j) acc[j] += __shfl_xor(acc[j], 32);
    if (half == 0) {
        const float4* b4 = (const float4*)bias;
        float4 ba = b4[hl * 2], bb = b4[hl * 2 + 1];
        float v0 = fmaf(acc[0], rd, ba.x), v1 = fmaf(acc[1], rd, ba.y);
        float v2 = fmaf(acc[2], rd, ba.z), v3 = fmaf(acc[3], rd, ba.w);
        float v4 = fmaf(acc[4], rd, bb.x), v5 = fmaf(acc[5], rd, bb.y);
        float v6 = fmaf(acc[6], rd, bb.z), v7 = fmaf(acc[7], rd, bb.w);
        f16x8 o;
        o[0] = (f16)(v0 > 0.f ? v0 : 0.f); o[1] = (f16)(v1 > 0.f ? v1 : 0.f);
        o[2] = (f16)(v2 > 0.f ? v2 : 0.f); o[3] = (f16)(v3 > 0.f ? v3 : 0.f);
        o[4] = (f16)(v4 > 0.f ? v4 : 0.f); o[5] = (f16)(v5 > 0.f ? v5 : 0.f);
        o[6] = (f16)(v6 > 0.f ? v6 : 0.f); o[7] = (f16)(v7 > 0.f ? v7 : 0.f);
        ((f16x8*)hbuf)[n * 32 + hl] = o;
    }
}

// ================= Layer 2 GEMM (MFMA): xp2h = f16(h @ W2) =================
__global__ __launch_bounds__(256) void k_gemm2m(
    const f16* __restrict__ hbuf, const f16* __restrict__ W2p,
    f16* __restrict__ xp2h)
{
    const int wv = threadIdx.x >> 6, lane = threadIdx.x & 63;
    const int l15 = lane & 15, quad = lane >> 4;
    const int rowtile = blockIdx.x * 4 + wv;
    if (rowtile >= MTILES) return;
    const int rowbase = rowtile * 16;

    const f16x8* Wf = (const f16x8*)W2p;
    f32x4 acc[4];
#pragma unroll
    for (int ct = 0; ct < 4; ++ct) acc[ct] = (f32x4){0.f, 0.f, 0.f, 0.f};
    const f16* hrow = hbuf + (rowbase + l15) * F1 + quad * 8;
#pragma unroll
    for (int kb = 0; kb < 8; ++kb) {
        f16x8 a = *(const f16x8*)(hrow + kb * 32);
#pragma unroll
        for (int ct = 0; ct < 4; ++ct) {
            f16x8 b = Wf[(ct * 8 + kb) * 64 + lane];
            acc[ct] = __builtin_amdgcn_mfma_f32_16x16x32_f16(a, b, acc[ct], 0, 0, 0);
        }
    }
    const int orow = rowbase + quad * 4;
#pragma unroll
    for (int ct = 0; ct < 4; ++ct) {
#pragma unroll
        for (int r = 0; r < 4; ++r)
            xp2h[(orow + r) * OUTD + ct * 16 + l15] = (f16)acc[ct][r];
    }
}

// ================= Layer 2 scores from xp2h =================
__global__ __launch_bounds__(256) void k_score2(
    const f16* __restrict__ xp2h, const float* __restrict__ as2,
    const float* __restrict__ ad2, float* __restrict__ ssrc,
    float* __restrict__ sdst)
{
    const int wv = threadIdx.x >> 6, lane = threadIdx.x & 63;
    const int n = blockIdx.x * 4 + wv;
    float v = (float)xp2h[n * OUTD + lane];
    float p = v * as2[lane];
    float q = v * ad2[lane];
#pragma unroll
    for (int off = 32; off; off >>= 1) {
        p += __shfl_xor(p, off);
        q += __shfl_xor(q, off);
    }
    if (lane == 0) { ssrc[n] = p; sdst[n] = q; }
}

// ===== Layer 2 fused softmax+aggregate+bias -> d_out: b128 gather =====
// chunk = 64 edges (phase A: lane=edge). Phase B: 8 edges per step, 8 lanes
// x b128 per edge row (128B). lane accumulates ch=(l&7)*8+j over edge group l>>3.
__global__ __launch_bounds__(256) void k_agg2(
    const int* __restrict__ row_ptr, const int* __restrict__ csr_src,
    const float* __restrict__ ssrc, const float* __restrict__ sdst,
    const f16* __restrict__ xp2h, const float* __restrict__ bias,
    float* __restrict__ out)
{
    const int wv = threadIdx.x >> 6, l = threadIdx.x & 63;
    const int n = blockIdx.x * 4 + wv;
    const int grp = l >> 3, sub = l & 7;
    const float sd = sdst[n];
    const int jbeg = row_ptr[n], jend = row_ptr[n + 1];
    const f16x8* xv = (const f16x8*)xp2h;

    float den = 0.f;
    float acc[8] = {0.f,0.f,0.f,0.f,0.f,0.f,0.f,0.f};
    for (int base = jbeg; base < jend; base += 64) {
        int c = jend - base; if (c > 64) c = 64;
        int s = 0; float ex = 0.f;
        if (l < c) {
            s = csr_src[base + l];
            float e = ssrc[s] + sd;
            e = e > 0.f ? e : 0.2f * e;
            ex = __expf(e);
        }
        den += ex;
        for (int i = 0; 8 * i < c; ++i) {
            int eidx = 8 * i + grp;
            int   se = __shfl(s, eidx);
            float ae = __shfl(ex, eidx);
            f16x8 v = xv[se * 8 + sub];
#pragma unroll
            for (int j = 0; j < 8; ++j) acc[j] = fmaf(ae, (float)v[j], acc[j]);
        }
    }
#pragma unroll
    for (int off = 32; off; off >>= 1) den += __shfl_xor(den, off);
    const float rd = 1.f / (den + 1e-16f);
#pragma unroll
    for (int j = 0; j < 8; ++j) {
        acc[j] += __shfl_xor(acc[j], 8);
        acc[j] += __shfl_xor(acc[j], 16);
        acc[j] += __shfl_xor(acc[j], 32);
    }
    if (grp == 0) {
        const float4* b4 = (const float4*)bias;
        float4 ba = b4[sub * 2], bb = b4[sub * 2 + 1];
        float4 o0, o1;
        o0.x = fmaf(acc[0], rd, ba.x); o0.y = fmaf(acc[1], rd, ba.y);
        o0.z = fmaf(acc[2], rd, ba.z); o0.w = fmaf(acc[3], rd, ba.w);
        o1.x = fmaf(acc[4], rd, bb.x); o1.y = fmaf(acc[5], rd, bb.y);
        o1.z = fmaf(acc[6], rd, bb.z); o1.w = fmaf(acc[7], rd, bb.w);
        float4* ov = (float4*)out + n * 16 + sub * 2;
        ov[0] = o0; ov[1] = o1;
    }
}

extern "C" void kernel_launch(void* const* d_in, const int* in_sizes, int n_in,
                              void* d_out, int out_size, void* d_ws, size_t ws_size,
                              hipStream_t stream)
{
    (void)in_sizes; (void)n_in; (void)out_size; (void)ws_size;
    const float* x   = (const float*)d_in[0];
    const int*   ei  = (const int*)d_in[1];
    const float* W1  = (const float*)d_in[2];
    const float* as1 = (const float*)d_in[3];
    const float* ad1 = (const float*)d_in[4];
    const float* b1  = (const float*)d_in[5];
    const float* W2  = (const float*)d_in[6];
    const float* as2 = (const float*)d_in[7];
    const float* ad2 = (const float*)d_in[8];
    const float* b2  = (const float*)d_in[9];
    float* out = (float*)d_out;

    // workspace layout (~58 MB)
    f16* xp1h   = (f16*)d_ws;                              // N*256 f16 (25.6 MB)
    f16* hbuf   = xp1h + (size_t)NODES * F1;               // N*256 f16 (25.6 MB)
    f16* W1p    = hbuf + (size_t)NODES * F1;               // 32768 f16
    f16* W2p    = W1p + 32768;                             // 16384 f16
    float* ssrc1 = (float*)(W2p + 16384);                  // N*4
    float* sdst1 = ssrc1 + (size_t)NODES * HEADS;          // N*4
    float* ssrc2 = sdst1 + (size_t)NODES * HEADS;          // N
    float* sdst2 = ssrc2 + (size_t)NODES;                  // N
    int* deg     = (int*)(sdst2 + (size_t)NODES);          // N
    int* row_ptr = deg + NODES;                            // N+1
    int* bsum    = row_ptr + NODES + 1;                    // 256
    int* cursor  = bsum + 256;                             // N
    int* csr_src = cursor + NODES;                         // NE2
    f16* xp2h    = xp1h;   // alias: xp1h dead after k_agg1

    // ---- CSR build (dst-sorted) + W pre-swizzle ----
    hipMemsetAsync(deg, 0, sizeof(int) * NODES, stream);
    k_hist<<<(NE2 + 255) / 256, 256, 0, stream>>>(ei, deg);
    k_prepW1<<<128, 256, 0, stream>>>(W1, W1p);
    k_prepW2<<<64, 256, 0, stream>>>(W2, W2p);
    k_scan1<<<NBLK_SCAN, 256, 0, stream>>>(deg, row_ptr, bsum);
    k_scan2<<<1, 256, 0, stream>>>(bsum);
    k_scan3<<<NBLK_SCAN, 256, 0, stream>>>(row_ptr, bsum, cursor);
    k_scatter<<<(NE2 + 255) / 256, 256, 0, stream>>>(ei, cursor, csr_src);

    // ---- layer 1 ----
    k_gemm1m<<<(MTILES + 3) / 4, 256, 0, stream>>>(x, W1p, xp1h);
    k_score1<<<NODES / 4, 256, 0, stream>>>(xp1h, as1, ad1, ssrc1, sdst1);
    k_agg1<<<NODES / 4, 256, 0, stream>>>(row_ptr, csr_src, ssrc1, sdst1,
                                          xp1h, b1, hbuf);

    // ---- layer 2 ----
    k_gemm2m<<<(MTILES + 3) / 4, 256, 0, stream>>>(hbuf, W2p, xp2h);
    k_score2<<<NODES / 4, 256, 0, stream>>>(xp2h, as2, ad2, ssrc2, sdst2);
    k_agg2<<<NODES / 4, 256, 0, stream>>>(row_ptr, csr_src, ssrc2, sdst2,
                                          xp2h, b2, out);
}

// Round 8
// 326.128 us; speedup vs baseline: 4.6682x; 1.0142x over previous
//
#include <hip/hip_runtime.h>
#include <hip/hip_bf16.h>
#include <hip/hip_fp16.h>

// Problem constants (from reference)
#define NODES 50000
#define NEDGE 800000
#define NE2   850000   // NEDGE + NODES self-loops
#define INDIM 128
#define F1    256      // HEADS*HID
#define HEADS 4
#define HID   64
#define OUTD  64
#define NBLK_SCAN 196  // ceil(NODES/256)
#define MTILES 3125    // NODES/16

typedef _Float16 f16;
typedef _Float16 f16x8 __attribute__((ext_vector_type(8)));
typedef float    f32x4 __attribute__((ext_vector_type(4)));

// ================= CSR build =================
// histogram real edges only; self-loops folded in at scan time (+1)
__global__ void k_hist(const int* __restrict__ ei, int* __restrict__ deg)
{
    int i = blockIdx.x * 256 + threadIdx.x;
    if (i >= NEDGE) return;
    atomicAdd(&deg[ei[NEDGE + i]], 1);
}

// per-256-chunk exclusive scan of (deg+1); chunk total to bsum
__global__ void k_scan1(const int* __restrict__ deg, int* __restrict__ excl,
                        int* __restrict__ bsum)
{
    __shared__ int sh[256];
    int t = threadIdx.x;
    int i = blockIdx.x * 256 + t;
    int v = (i < NODES) ? (deg[i] + 1) : 0;   // +1 = self loop
    sh[t] = v; __syncthreads();
    for (int off = 1; off < 256; off <<= 1) {
        int tv = (t >= off) ? sh[t - off] : 0;
        __syncthreads();
        sh[t] += tv;
        __syncthreads();
    }
    if (i < NODES) excl[i] = sh[t] - v;
    if (t == 255) bsum[blockIdx.x] = sh[255];
}

// add cross-chunk prefix (block-local reduction of bsum[0..bid)) + init cursor
__global__ void k_scan3(int* __restrict__ row_ptr, const int* __restrict__ bsum,
                        int* __restrict__ cursor)
{
    __shared__ int ssum[4];
    const int t = threadIdx.x, wv = t >> 6, lane = t & 63;
    int v = (t < (int)blockIdx.x) ? bsum[t] : 0;
#pragma unroll
    for (int off = 32; off; off >>= 1) v += __shfl_xor(v, off);
    if (lane == 0) ssum[wv] = v;
    __syncthreads();
    int prefix = ssum[0] + ssum[1] + ssum[2] + ssum[3];
    int i = blockIdx.x * 256 + t;
    if (i < NODES) {
        int r = row_ptr[i] + prefix;
        row_ptr[i] = r;
        cursor[i] = r;
    }
    if (i == 0) row_ptr[NODES] = NE2;
}

__global__ void k_scatter(const int* __restrict__ ei, int* __restrict__ cursor,
                          int* __restrict__ csr_src)
{
    int i = blockIdx.x * 256 + threadIdx.x;
    if (i >= NE2) return;
    int s, d;
    if (i < NEDGE) { s = ei[i]; d = ei[NEDGE + i]; } else { s = d = i - NEDGE; }
    int pos = atomicAdd(&cursor[d], 1);
    csr_src[pos] = s;
}

// ================= W pre-swizzle into MFMA B-fragment order ===============
__global__ void k_prepW1(const float* __restrict__ W1, f16* __restrict__ W1p)
{
    int idx = blockIdx.x * 256 + threadIdx.x;   // < 32768
    int j = idx & 7, l = (idx >> 3) & 63, fi = idx >> 9;
    int kb = fi & 3, ct = fi >> 2;
    int k = kb * 32 + (l >> 4) * 8 + j;
    int col = ct * 16 + (l & 15);
    W1p[idx] = (f16)W1[k * F1 + col];
}

__global__ void k_prepW2(const float* __restrict__ W2, f16* __restrict__ W2p)
{
    int idx = blockIdx.x * 256 + threadIdx.x;   // < 16384
    int j = idx & 7, l = (idx >> 3) & 63, fi = idx >> 9;
    int kb = fi & 7, ct = fi >> 3;
    int k = kb * 32 + (l >> 4) * 8 + j;
    int col = ct * 16 + (l & 15);
    W2p[idx] = (f16)W2[k * OUTD + col];
}

// ====== Layer 1 GEMM (MFMA) + fused attention scores =====================
__global__ __launch_bounds__(256) void k_gemm1m(
    const float* __restrict__ x, const f16* __restrict__ W1p,
    const float* __restrict__ as1, const float* __restrict__ ad1,
    f16* __restrict__ xp1h, float* __restrict__ ssrc, float* __restrict__ sdst)
{
    const int wv = threadIdx.x >> 6, lane = threadIdx.x & 63;
    const int l15 = lane & 15, quad = lane >> 4;
    const int rowtile = blockIdx.x * 4 + wv;
    if (rowtile >= MTILES) return;
    const int rowbase = rowtile * 16;

    f16x8 afrag[4];
    const float* xrow = x + (rowbase + l15) * INDIM + quad * 8;
#pragma unroll
    for (int kb = 0; kb < 4; ++kb) {
        float4 u0 = *(const float4*)(xrow + kb * 32);
        float4 u1 = *(const float4*)(xrow + kb * 32 + 4);
        f16x8 a;
        a[0] = (f16)u0.x; a[1] = (f16)u0.y; a[2] = (f16)u0.z; a[3] = (f16)u0.w;
        a[4] = (f16)u1.x; a[5] = (f16)u1.y; a[6] = (f16)u1.z; a[7] = (f16)u1.w;
        afrag[kb] = a;
    }

    const f16x8* Wf = (const f16x8*)W1p;
    f32x4 acc[16];
#pragma unroll
    for (int ct = 0; ct < 16; ++ct) acc[ct] = (f32x4){0.f, 0.f, 0.f, 0.f};
#pragma unroll
    for (int ct = 0; ct < 16; ++ct) {
#pragma unroll
        for (int kb = 0; kb < 4; ++kb) {
            f16x8 b = Wf[(ct * 4 + kb) * 64 + lane];
            acc[ct] = __builtin_amdgcn_mfma_f32_16x16x32_f16(afrag[kb], b, acc[ct], 0, 0, 0);
        }
    }
    // stores: C/D col = ct*16 + l15, row = quad*4 + r
    const int orow = rowbase + quad * 4;
#pragma unroll
    for (int ct = 0; ct < 16; ++ct) {
#pragma unroll
        for (int r = 0; r < 4; ++r)
            xp1h[(orow + r) * F1 + ct * 16 + l15] = (f16)acc[ct][r];
    }
    // fused scores: ps[h][r] = sum over cols in head h
    float ps[4][4], pd[4][4];
#pragma unroll
    for (int h = 0; h < 4; ++h)
#pragma unroll
        for (int r = 0; r < 4; ++r) { ps[h][r] = 0.f; pd[h][r] = 0.f; }
#pragma unroll
    for (int ct = 0; ct < 16; ++ct) {
        float av = as1[ct * 16 + l15];
        float dv = ad1[ct * 16 + l15];
        int h = ct >> 2;
#pragma unroll
        for (int r = 0; r < 4; ++r) {
            ps[h][r] = fmaf(acc[ct][r], av, ps[h][r]);
            pd[h][r] = fmaf(acc[ct][r], dv, pd[h][r]);
        }
    }
#pragma unroll
    for (int off = 8; off; off >>= 1) {
#pragma unroll
        for (int h = 0; h < 4; ++h)
#pragma unroll
            for (int r = 0; r < 4; ++r) {
                ps[h][r] += __shfl_xor(ps[h][r], off);
                pd[h][r] += __shfl_xor(pd[h][r], off);
            }
    }
    if (l15 == 0) {
#pragma unroll
        for (int r = 0; r < 4; ++r) {
            int row = orow + r;
            float4 vs = {ps[0][r], ps[1][r], ps[2][r], ps[3][r]};
            float4 vd = {pd[0][r], pd[1][r], pd[2][r], pd[3][r]};
            ((float4*)ssrc)[row] = vs;
            ((float4*)sdst)[row] = vd;
        }
    }
}

// ===== Layer 1 fused softmax+aggregate: block per node, 4-way edge split ====
// Each wave: phase A lane (eq=l&15, ph=l>>4) -> exp(edge,head); phase B per
// edge pair, half-wave x b128 loads the 512B row; LDS combine across waves.
__global__ __launch_bounds__(256) void k_agg1(
    const int* __restrict__ row_ptr, const int* __restrict__ csr_src,
    const float* __restrict__ ssrc, const float* __restrict__ sdst,
    const f16* __restrict__ xp1h, const float* __restrict__ bias,
    f16* __restrict__ hbuf)
{
    __shared__ float accs[4][32][9];   // [wave][hl][ch j] pad->9 (bank-safe)
    __shared__ float dens[4][4];       // [wave][head]
    const int t = threadIdx.x, wv = t >> 6, l = t & 63;
    const int n = blockIdx.x;
    const int eq = l & 15, ph = l >> 4;
    const int hl = l & 31, half = l >> 5;
    const int exsel = ((hl >> 3) << 4);
    const float sd = sdst[n * HEADS + ph];
    const int jbeg = row_ptr[n], jend = row_ptr[n + 1];
    const int deg = jend - jbeg;
    const int seg = (deg + 3) >> 2;
    const int wbeg = jbeg + wv * seg;
    int wend = wbeg + seg; if (wend > jend) wend = jend;
    const f16x8* xv = (const f16x8*)xp1h;

    float den = 0.f;
    float acc[8] = {0.f,0.f,0.f,0.f,0.f,0.f,0.f,0.f};
    for (int base = wbeg; base < wend; base += 16) {
        int c = wend - base; if (c > 16) c = 16;
        int s = 0; float ex = 0.f;
        if (eq < c) {
            s = csr_src[base + eq];
            float e = ssrc[s * HEADS + ph] + sd;
            e = e > 0.f ? e : 0.2f * e;
            ex = __expf(e);
        }
        den += ex;
        for (int p = 0; 2 * p < c; ++p) {
            int eidx = 2 * p + half;
            int   se = __shfl(s, eidx);
            float ae = __shfl(ex, eidx + exsel);   // ex=0 for eidx>=c
            f16x8 v = xv[se * 32 + hl];
#pragma unroll
            for (int j = 0; j < 8; ++j) acc[j] = fmaf(ae, (float)v[j], acc[j]);
        }
    }
    // intra-wave: per-head den (reduce within 16-lane groups)
#pragma unroll
    for (int off = 8; off; off >>= 1) den += __shfl_xor(den, off);
    // combine edge-parity halves of acc
#pragma unroll
    for (int j = 0; j < 8; ++j) acc[j] += __shfl_xor(acc[j], 32);
    if (eq == 0) dens[wv][ph] = den;
    if (half == 0) {
#pragma unroll
        for (int j = 0; j < 8; ++j) accs[wv][hl][j] = acc[j];
    }
    __syncthreads();
    if (wv == 0 && l < 32) {
        float a[8];
#pragma unroll
        for (int j = 0; j < 8; ++j)
            a[j] = accs[0][l][j] + accs[1][l][j] + accs[2][l][j] + accs[3][l][j];
        int hh = l >> 3;
        float dh = dens[0][hh] + dens[1][hh] + dens[2][hh] + dens[3][hh];
        float rd = 1.f / (dh + 1e-16f);
        const float4* b4 = (const float4*)bias;
        float4 ba = b4[l * 2], bb = b4[l * 2 + 1];
        float v0 = fmaf(a[0], rd, ba.x), v1 = fmaf(a[1], rd, ba.y);
        float v2 = fmaf(a[2], rd, ba.z), v3 = fmaf(a[3], rd, ba.w);
        float v4 = fmaf(a[4], rd, bb.x), v5 = fmaf(a[5], rd, bb.y);
        float v6 = fmaf(a[6], rd, bb.z), v7 = fmaf(a[7], rd, bb.w);
        f16x8 o;
        o[0] = (f16)(v0 > 0.f ? v0 : 0.f); o[1] = (f16)(v1 > 0.f ? v1 : 0.f);
        o[2] = (f16)(v2 > 0.f ? v2 : 0.f); o[3] = (f16)(v3 > 0.f ? v3 : 0.f);
        o[4] = (f16)(v4 > 0.f ? v4 : 0.f); o[5] = (f16)(v5 > 0.f ? v5 : 0.f);
        o[6] = (f16)(v6 > 0.f ? v6 : 0.f); o[7] = (f16)(v7 > 0.f ? v7 : 0.f);
        ((f16x8*)hbuf)[n * 32 + l] = o;
    }
}

// ====== Layer 2 GEMM (MFMA) + fused scores ================================
__global__ __launch_bounds__(256) void k_gemm2m(
    const f16* __restrict__ hbuf, const f16* __restrict__ W2p,
    const float* __restrict__ as2, const float* __restrict__ ad2,
    f16* __restrict__ xp2h, float* __restrict__ ssrc, float* __restrict__ sdst)
{
    const int wv = threadIdx.x >> 6, lane = threadIdx.x & 63;
    const int l15 = lane & 15, quad = lane >> 4;
    const int rowtile = blockIdx.x * 4 + wv;
    if (rowtile >= MTILES) return;
    const int rowbase = rowtile * 16;

    const f16x8* Wf = (const f16x8*)W2p;
    f32x4 acc[4];
#pragma unroll
    for (int ct = 0; ct < 4; ++ct) acc[ct] = (f32x4){0.f, 0.f, 0.f, 0.f};
    const f16* hrow = hbuf + (rowbase + l15) * F1 + quad * 8;
#pragma unroll
    for (int kb = 0; kb < 8; ++kb) {
        f16x8 a = *(const f16x8*)(hrow + kb * 32);
#pragma unroll
        for (int ct = 0; ct < 4; ++ct) {
            f16x8 b = Wf[(ct * 8 + kb) * 64 + lane];
            acc[ct] = __builtin_amdgcn_mfma_f32_16x16x32_f16(a, b, acc[ct], 0, 0, 0);
        }
    }
    const int orow = rowbase + quad * 4;
#pragma unroll
    for (int ct = 0; ct < 4; ++ct) {
#pragma unroll
        for (int r = 0; r < 4; ++r)
            xp2h[(orow + r) * OUTD + ct * 16 + l15] = (f16)acc[ct][r];
    }
    float ps[4] = {0.f,0.f,0.f,0.f}, pd[4] = {0.f,0.f,0.f,0.f};
#pragma unroll
    for (int ct = 0; ct < 4; ++ct) {
        float av = as2[ct * 16 + l15];
        float dv = ad2[ct * 16 + l15];
#pragma unroll
        for (int r = 0; r < 4; ++r) {
            ps[r] = fmaf(acc[ct][r], av, ps[r]);
            pd[r] = fmaf(acc[ct][r], dv, pd[r]);
        }
    }
#pragma unroll
    for (int off = 8; off; off >>= 1) {
#pragma unroll
        for (int r = 0; r < 4; ++r) {
            ps[r] += __shfl_xor(ps[r], off);
            pd[r] += __shfl_xor(pd[r], off);
        }
    }
    if (l15 == 0) {
#pragma unroll
        for (int r = 0; r < 4; ++r) {
            ssrc[orow + r] = ps[r];
            sdst[orow + r] = pd[r];
        }
    }
}

// ===== Layer 2 fused softmax+aggregate+bias -> d_out: b128 gather =====
__global__ __launch_bounds__(256) void k_agg2(
    const int* __restrict__ row_ptr, const int* __restrict__ csr_src,
    const float* __restrict__ ssrc, const float* __restrict__ sdst,
    const f16* __restrict__ xp2h, const float* __restrict__ bias,
    float* __restrict__ out)
{
    const int wv = threadIdx.x >> 6, l = threadIdx.x & 63;
    const int n = blockIdx.x * 4 + wv;
    const int grp = l >> 3, sub = l & 7;
    const float sd = sdst[n];
    const int jbeg = row_ptr[n], jend = row_ptr[n + 1];
    const f16x8* xv = (const f16x8*)xp2h;

    float den = 0.f;
    float acc[8] = {0.f,0.f,0.f,0.f,0.f,0.f,0.f,0.f};
    for (int base = jbeg; base < jend; base += 64) {
        int c = jend - base; if (c > 64) c = 64;
        int s = 0; float ex = 0.f;
        if (l < c) {
            s = csr_src[base + l];
            float e = ssrc[s] + sd;
            e = e > 0.f ? e : 0.2f * e;
            ex = __expf(e);
        }
        den += ex;
        for (int i = 0; 8 * i < c; ++i) {
            int eidx = 8 * i + grp;
            int   se = __shfl(s, eidx);
            float ae = __shfl(ex, eidx);
            f16x8 v = xv[se * 8 + sub];
#pragma unroll
            for (int j = 0; j < 8; ++j) acc[j] = fmaf(ae, (float)v[j], acc[j]);
        }
    }
#pragma unroll
    for (int off = 32; off; off >>= 1) den += __shfl_xor(den, off);
    const float rd = 1.f / (den + 1e-16f);
#pragma unroll
    for (int j = 0; j < 8; ++j) {
        acc[j] += __shfl_xor(acc[j], 8);
        acc[j] += __shfl_xor(acc[j], 16);
        acc[j] += __shfl_xor(acc[j], 32);
    }
    if (grp == 0) {
        const float4* b4 = (const float4*)bias;
        float4 ba = b4[sub * 2], bb = b4[sub * 2 + 1];
        float4 o0, o1;
        o0.x = fmaf(acc[0], rd, ba.x); o0.y = fmaf(acc[1], rd, ba.y);
        o0.z = fmaf(acc[2], rd, ba.z); o0.w = fmaf(acc[3], rd, ba.w);
        o1.x = fmaf(acc[4], rd, bb.x); o1.y = fmaf(acc[5], rd, bb.y);
        o1.z = fmaf(acc[6], rd, bb.z); o1.w = fmaf(acc[7], rd, bb.w);
        float4* ov = (float4*)out + n * 16 + sub * 2;
        ov[0] = o0; ov[1] = o1;
    }
}

extern "C" void kernel_launch(void* const* d_in, const int* in_sizes, int n_in,
                              void* d_out, int out_size, void* d_ws, size_t ws_size,
                              hipStream_t stream)
{
    (void)in_sizes; (void)n_in; (void)out_size; (void)ws_size;
    const float* x   = (const float*)d_in[0];
    const int*   ei  = (const int*)d_in[1];
    const float* W1  = (const float*)d_in[2];
    const float* as1 = (const float*)d_in[3];
    const float* ad1 = (const float*)d_in[4];
    const float* b1  = (const float*)d_in[5];
    const float* W2  = (const float*)d_in[6];
    const float* as2 = (const float*)d_in[7];
    const float* ad2 = (const float*)d_in[8];
    const float* b2  = (const float*)d_in[9];
    float* out = (float*)d_out;

    // workspace layout (~58 MB)
    f16* xp1h   = (f16*)d_ws;                              // N*256 f16 (25.6 MB)
    f16* hbuf   = xp1h + (size_t)NODES * F1;               // N*256 f16 (25.6 MB)
    f16* W1p    = hbuf + (size_t)NODES * F1;               // 32768 f16
    f16* W2p    = W1p + 32768;                             // 16384 f16
    float* ssrc1 = (float*)(W2p + 16384);                  // N*4
    float* sdst1 = ssrc1 + (size_t)NODES * HEADS;          // N*4
    float* ssrc2 = sdst1 + (size_t)NODES * HEADS;          // N
    float* sdst2 = ssrc2 + (size_t)NODES;                  // N
    int* deg     = (int*)(sdst2 + (size_t)NODES);          // N
    int* row_ptr = deg + NODES;                            // N+1
    int* bsum    = row_ptr + NODES + 1;                    // 256
    int* cursor  = bsum + 256;                             // N
    int* csr_src = cursor + NODES;                         // NE2
    f16* xp2h    = xp1h;   // alias: xp1h dead after k_agg1

    // ---- CSR build (dst-sorted) + W pre-swizzle ----
    hipMemsetAsync(deg, 0, sizeof(int) * NODES, stream);
    k_hist<<<(NEDGE + 255) / 256, 256, 0, stream>>>(ei, deg);
    k_prepW1<<<128, 256, 0, stream>>>(W1, W1p);
    k_prepW2<<<64, 256, 0, stream>>>(W2, W2p);
    k_scan1<<<NBLK_SCAN, 256, 0, stream>>>(deg, row_ptr, bsum);
    k_scan3<<<NBLK_SCAN, 256, 0, stream>>>(row_ptr, bsum, cursor);
    k_scatter<<<(NE2 + 255) / 256, 256, 0, stream>>>(ei, cursor, csr_src);

    // ---- layer 1 ----
    k_gemm1m<<<(MTILES + 3) / 4, 256, 0, stream>>>(x, W1p, as1, ad1,
                                                   xp1h, ssrc1, sdst1);
    k_agg1<<<NODES, 256, 0, stream>>>(row_ptr, csr_src, ssrc1, sdst1,
                                      xp1h, b1, hbuf);

    // ---- layer 2 ----
    k_gemm2m<<<(MTILES + 3) / 4, 256, 0, stream>>>(hbuf, W2p, as2, ad2,
                                                   xp2h, ssrc2, sdst2);
    k_agg2<<<NODES / 4, 256, 0, stream>>>(row_ptr, csr_src, ssrc2, sdst2,
                                          xp2h, b2, out);
}

// Round 9
// 297.642 us; speedup vs baseline: 5.1149x; 1.0957x over previous
//
#include <hip/hip_runtime.h>
#include <hip/hip_bf16.h>
#include <hip/hip_fp16.h>

// Problem constants (from reference)
#define NODES 50000
#define NEDGE 800000
#define NE2   850000   // NEDGE + NODES self-loops
#define INDIM 128
#define F1    256      // HEADS*HID
#define HEADS 4
#define HID   64
#define OUTD  64
#define NBLK_SCAN 196  // ceil(NODES/256)
#define MTILES 3125    // NODES/16

typedef _Float16 f16;
typedef _Float16 f16x8 __attribute__((ext_vector_type(8)));
typedef float    f32x4 __attribute__((ext_vector_type(4)));

// ================= CSR build =================
// histogram real edges only; self-loops folded in at scan time (+1)
__global__ void k_hist(const int* __restrict__ ei, int* __restrict__ deg)
{
    int i = blockIdx.x * 256 + threadIdx.x;
    if (i >= NEDGE) return;
    atomicAdd(&deg[ei[NEDGE + i]], 1);
}

// per-256-chunk exclusive scan of (deg+1); chunk total to bsum
__global__ void k_scan1(const int* __restrict__ deg, int* __restrict__ excl,
                        int* __restrict__ bsum)
{
    __shared__ int sh[256];
    int t = threadIdx.x;
    int i = blockIdx.x * 256 + t;
    int v = (i < NODES) ? (deg[i] + 1) : 0;   // +1 = self loop
    sh[t] = v; __syncthreads();
    for (int off = 1; off < 256; off <<= 1) {
        int tv = (t >= off) ? sh[t - off] : 0;
        __syncthreads();
        sh[t] += tv;
        __syncthreads();
    }
    if (i < NODES) excl[i] = sh[t] - v;
    if (t == 255) bsum[blockIdx.x] = sh[255];
}

// add cross-chunk prefix (block-local reduction of bsum[0..bid)) + init cursor
__global__ void k_scan3(int* __restrict__ row_ptr, const int* __restrict__ bsum,
                        int* __restrict__ cursor)
{
    __shared__ int ssum[4];
    const int t = threadIdx.x, wv = t >> 6, lane = t & 63;
    int v = (t < (int)blockIdx.x) ? bsum[t] : 0;
#pragma unroll
    for (int off = 32; off; off >>= 1) v += __shfl_xor(v, off);
    if (lane == 0) ssum[wv] = v;
    __syncthreads();
    int prefix = ssum[0] + ssum[1] + ssum[2] + ssum[3];
    int i = blockIdx.x * 256 + t;
    if (i < NODES) {
        int r = row_ptr[i] + prefix;
        row_ptr[i] = r;
        cursor[i] = r;
    }
    if (i == 0) row_ptr[NODES] = NE2;
}

__global__ void k_scatter(const int* __restrict__ ei, int* __restrict__ cursor,
                          int* __restrict__ csr_src)
{
    int i = blockIdx.x * 256 + threadIdx.x;
    if (i >= NE2) return;
    int s, d;
    if (i < NEDGE) { s = ei[i]; d = ei[NEDGE + i]; } else { s = d = i - NEDGE; }
    int pos = atomicAdd(&cursor[d], 1);
    csr_src[pos] = s;
}

// ================= W pre-swizzle into MFMA B-fragment order (merged) =======
__global__ void k_prepW(const float* __restrict__ W1, const float* __restrict__ W2,
                        f16* __restrict__ W1p, f16* __restrict__ W2p)
{
    int idx = blockIdx.x * 256 + threadIdx.x;   // < 49152
    if (idx < 32768) {
        int j = idx & 7, l = (idx >> 3) & 63, fi = idx >> 9;
        int kb = fi & 3, ct = fi >> 2;
        int k = kb * 32 + (l >> 4) * 8 + j;
        int col = ct * 16 + (l & 15);
        W1p[idx] = (f16)W1[k * F1 + col];
    } else {
        int i2 = idx - 32768;                   // < 16384
        int j = i2 & 7, l = (i2 >> 3) & 63, fi = i2 >> 9;
        int kb = fi & 7, ct = fi >> 3;
        int k = kb * 32 + (l >> 4) * 8 + j;
        int col = ct * 16 + (l & 15);
        W2p[i2] = (f16)W2[k * OUTD + col];
    }
}

// ====== Layer 1 GEMM (MFMA) + fused attention scores =====================
__global__ __launch_bounds__(256) void k_gemm1m(
    const float* __restrict__ x, const f16* __restrict__ W1p,
    const float* __restrict__ as1, const float* __restrict__ ad1,
    f16* __restrict__ xp1h, float* __restrict__ ssrc, float* __restrict__ sdst)
{
    const int wv = threadIdx.x >> 6, lane = threadIdx.x & 63;
    const int l15 = lane & 15, quad = lane >> 4;
    const int rowtile = blockIdx.x * 4 + wv;
    if (rowtile >= MTILES) return;
    const int rowbase = rowtile * 16;

    f16x8 afrag[4];
    const float* xrow = x + (rowbase + l15) * INDIM + quad * 8;
#pragma unroll
    for (int kb = 0; kb < 4; ++kb) {
        float4 u0 = *(const float4*)(xrow + kb * 32);
        float4 u1 = *(const float4*)(xrow + kb * 32 + 4);
        f16x8 a;
        a[0] = (f16)u0.x; a[1] = (f16)u0.y; a[2] = (f16)u0.z; a[3] = (f16)u0.w;
        a[4] = (f16)u1.x; a[5] = (f16)u1.y; a[6] = (f16)u1.z; a[7] = (f16)u1.w;
        afrag[kb] = a;
    }

    const f16x8* Wf = (const f16x8*)W1p;
    f32x4 acc[16];
#pragma unroll
    for (int ct = 0; ct < 16; ++ct) acc[ct] = (f32x4){0.f, 0.f, 0.f, 0.f};
#pragma unroll
    for (int ct = 0; ct < 16; ++ct) {
#pragma unroll
        for (int kb = 0; kb < 4; ++kb) {
            f16x8 b = Wf[(ct * 4 + kb) * 64 + lane];
            acc[ct] = __builtin_amdgcn_mfma_f32_16x16x32_f16(afrag[kb], b, acc[ct], 0, 0, 0);
        }
    }
    // stores: C/D col = ct*16 + l15, row = quad*4 + r
    const int orow = rowbase + quad * 4;
#pragma unroll
    for (int ct = 0; ct < 16; ++ct) {
#pragma unroll
        for (int r = 0; r < 4; ++r)
            xp1h[(orow + r) * F1 + ct * 16 + l15] = (f16)acc[ct][r];
    }
    // fused scores: ps[h][r] = sum over cols in head h
    float ps[4][4], pd[4][4];
#pragma unroll
    for (int h = 0; h < 4; ++h)
#pragma unroll
        for (int r = 0; r < 4; ++r) { ps[h][r] = 0.f; pd[h][r] = 0.f; }
#pragma unroll
    for (int ct = 0; ct < 16; ++ct) {
        float av = as1[ct * 16 + l15];
        float dv = ad1[ct * 16 + l15];
        int h = ct >> 2;
#pragma unroll
        for (int r = 0; r < 4; ++r) {
            ps[h][r] = fmaf(acc[ct][r], av, ps[h][r]);
            pd[h][r] = fmaf(acc[ct][r], dv, pd[h][r]);
        }
    }
#pragma unroll
    for (int off = 8; off; off >>= 1) {
#pragma unroll
        for (int h = 0; h < 4; ++h)
#pragma unroll
            for (int r = 0; r < 4; ++r) {
                ps[h][r] += __shfl_xor(ps[h][r], off);
                pd[h][r] += __shfl_xor(pd[h][r], off);
            }
    }
    if (l15 == 0) {
#pragma unroll
        for (int r = 0; r < 4; ++r) {
            int row = orow + r;
            float4 vs = {ps[0][r], ps[1][r], ps[2][r], ps[3][r]};
            float4 vd = {pd[0][r], pd[1][r], pd[2][r], pd[3][r]};
            ((float4*)ssrc)[row] = vs;
            ((float4*)sdst)[row] = vd;
        }
    }
}

// ===== Layer 1 fused softmax+aggregate: ONE wave per node, b128 gather =====
// chunk = 16 edges. Phase A: lane (eq=l&15, ph=l>>4) computes exp(edge,head).
// Phase B: per edge pair, half-wave (32 lanes x 16B) loads full 512B row;
// 2-step manual unroll keeps 2 gathers in flight per lane (latency hiding).
__global__ __launch_bounds__(256) void k_agg1(
    const int* __restrict__ row_ptr, const int* __restrict__ csr_src,
    const float* __restrict__ ssrc, const float* __restrict__ sdst,
    const f16* __restrict__ xp1h, const float* __restrict__ bias,
    f16* __restrict__ hbuf)
{
    const int wv = threadIdx.x >> 6, l = threadIdx.x & 63;
    const int n = blockIdx.x * 4 + wv;
    const int eq = l & 15, ph = l >> 4;        // phase-A role
    const int hl = l & 31;                     // half-lane: channel chunk
    const int half = l >> 5;                   // edge parity in phase B
    const int exsel = ((hl >> 3) << 4);        // channel-head -> exp lane block
    const float sd = sdst[n * HEADS + ph];
    const int jbeg = row_ptr[n], jend = row_ptr[n + 1];
    const f16x8* xv = (const f16x8*)xp1h;

    float den = 0.f;
    float acc[8] = {0.f,0.f,0.f,0.f,0.f,0.f,0.f,0.f};
    for (int base = jbeg; base < jend; base += 16) {
        int c = jend - base; if (c > 16) c = 16;
        int s = 0; float ex = 0.f;
        if (eq < c) {
            s = csr_src[base + eq];
            float e = ssrc[s * HEADS + ph] + sd;
            e = e > 0.f ? e : 0.2f * e;
            ex = __expf(e);
        }
        den += ex;
        int p = 0;
        for (; 2 * (p + 1) < c; p += 2) {       // two pair-steps: edges 2p..2p+3
            int ea = 2 * p + half, eb = 2 * p + 2 + half;
            int   sa = __shfl(s, ea),          sb = __shfl(s, eb);
            float aa = __shfl(ex, ea + exsel), ab = __shfl(ex, eb + exsel);
            f16x8 va = xv[sa * 32 + hl];
            f16x8 vb = xv[sb * 32 + hl];
#pragma unroll
            for (int j = 0; j < 8; ++j) acc[j] = fmaf(aa, (float)va[j], acc[j]);
#pragma unroll
            for (int j = 0; j < 8; ++j) acc[j] = fmaf(ab, (float)vb[j], acc[j]);
        }
        for (; 2 * p < c; ++p) {                // remaining pair (ex=0 pads)
            int eidx = 2 * p + half;
            int   se = __shfl(s, eidx);
            float ae = __shfl(ex, eidx + exsel);
            f16x8 v = xv[se * 32 + hl];
#pragma unroll
            for (int j = 0; j < 8; ++j) acc[j] = fmaf(ae, (float)v[j], acc[j]);
        }
    }
    // denominator: sum within each 16-lane head group, then pick channel-head's
#pragma unroll
    for (int off = 8; off; off >>= 1) den += __shfl_xor(den, off);
    float dh = __shfl(den, exsel);   // lane exsel = hh*16 holds head hh total
    const float rd = 1.f / (dh + 1e-16f);
    // combine edge-parity halves
#pragma unroll
    for (int j = 0; j < 8; ++j) acc[j] += __shfl_xor(acc[j], 32);
    if (half == 0) {
        const float4* b4 = (const float4*)bias;
        float4 ba = b4[hl * 2], bb = b4[hl * 2 + 1];
        float v0 = fmaf(acc[0], rd, ba.x), v1 = fmaf(acc[1], rd, ba.y);
        float v2 = fmaf(acc[2], rd, ba.z), v3 = fmaf(acc[3], rd, ba.w);
        float v4 = fmaf(acc[4], rd, bb.x), v5 = fmaf(acc[5], rd, bb.y);
        float v6 = fmaf(acc[6], rd, bb.z), v7 = fmaf(acc[7], rd, bb.w);
        f16x8 o;
        o[0] = (f16)(v0 > 0.f ? v0 : 0.f); o[1] = (f16)(v1 > 0.f ? v1 : 0.f);
        o[2] = (f16)(v2 > 0.f ? v2 : 0.f); o[3] = (f16)(v3 > 0.f ? v3 : 0.f);
        o[4] = (f16)(v4 > 0.f ? v4 : 0.f); o[5] = (f16)(v5 > 0.f ? v5 : 0.f);
        o[6] = (f16)(v6 > 0.f ? v6 : 0.f); o[7] = (f16)(v7 > 0.f ? v7 : 0.f);
        ((f16x8*)hbuf)[n * 32 + hl] = o;
    }
}

// ====== Layer 2 GEMM (MFMA) + fused scores ================================
__global__ __launch_bounds__(256) void k_gemm2m(
    const f16* __restrict__ hbuf, const f16* __restrict__ W2p,
    const float* __restrict__ as2, const float* __restrict__ ad2,
    f16* __restrict__ xp2h, float* __restrict__ ssrc, float* __restrict__ sdst)
{
    const int wv = threadIdx.x >> 6, lane = threadIdx.x & 63;
    const int l15 = lane & 15, quad = lane >> 4;
    const int rowtile = blockIdx.x * 4 + wv;
    if (rowtile >= MTILES) return;
    const int rowbase = rowtile * 16;

    const f16x8* Wf = (const f16x8*)W2p;
    f32x4 acc[4];
#pragma unroll
    for (int ct = 0; ct < 4; ++ct) acc[ct] = (f32x4){0.f, 0.f, 0.f, 0.f};
    const f16* hrow = hbuf + (rowbase + l15) * F1 + quad * 8;
#pragma unroll
    for (int kb = 0; kb < 8; ++kb) {
        f16x8 a = *(const f16x8*)(hrow + kb * 32);
#pragma unroll
        for (int ct = 0; ct < 4; ++ct) {
            f16x8 b = Wf[(ct * 8 + kb) * 64 + lane];
            acc[ct] = __builtin_amdgcn_mfma_f32_16x16x32_f16(a, b, acc[ct], 0, 0, 0);
        }
    }
    const int orow = rowbase + quad * 4;
#pragma unroll
    for (int ct = 0; ct < 4; ++ct) {
#pragma unroll
        for (int r = 0; r < 4; ++r)
            xp2h[(orow + r) * OUTD + ct * 16 + l15] = (f16)acc[ct][r];
    }
    float ps[4] = {0.f,0.f,0.f,0.f}, pd[4] = {0.f,0.f,0.f,0.f};
#pragma unroll
    for (int ct = 0; ct < 4; ++ct) {
        float av = as2[ct * 16 + l15];
        float dv = ad2[ct * 16 + l15];
#pragma unroll
        for (int r = 0; r < 4; ++r) {
            ps[r] = fmaf(acc[ct][r], av, ps[r]);
            pd[r] = fmaf(acc[ct][r], dv, pd[r]);
        }
    }
#pragma unroll
    for (int off = 8; off; off >>= 1) {
#pragma unroll
        for (int r = 0; r < 4; ++r) {
            ps[r] += __shfl_xor(ps[r], off);
            pd[r] += __shfl_xor(pd[r], off);
        }
    }
    if (l15 == 0) {
#pragma unroll
        for (int r = 0; r < 4; ++r) {
            ssrc[orow + r] = ps[r];
            sdst[orow + r] = pd[r];
        }
    }
}

// ===== Layer 2 fused softmax+aggregate+bias -> d_out: b128 gather =====
// chunk = 64 edges; phase B 2-step unroll (2 gathers in flight per lane)
__global__ __launch_bounds__(256) void k_agg2(
    const int* __restrict__ row_ptr, const int* __restrict__ csr_src,
    const float* __restrict__ ssrc, const float* __restrict__ sdst,
    const f16* __restrict__ xp2h, const float* __restrict__ bias,
    float* __restrict__ out)
{
    const int wv = threadIdx.x >> 6, l = threadIdx.x & 63;
    const int n = blockIdx.x * 4 + wv;
    const int grp = l >> 3, sub = l & 7;
    const float sd = sdst[n];
    const int jbeg = row_ptr[n], jend = row_ptr[n + 1];
    const f16x8* xv = (const f16x8*)xp2h;

    float den = 0.f;
    float acc[8] = {0.f,0.f,0.f,0.f,0.f,0.f,0.f,0.f};
    for (int base = jbeg; base < jend; base += 64) {
        int c = jend - base; if (c > 64) c = 64;
        int s = 0; float ex = 0.f;
        if (l < c) {
            s = csr_src[base + l];
            float e = ssrc[s] + sd;
            e = e > 0.f ? e : 0.2f * e;
            ex = __expf(e);
        }
        den += ex;
        int i = 0;
        for (; 8 * (i + 1) < c; i += 2) {
            int ea = 8 * i + grp, eb = 8 * i + 8 + grp;
            int   sa = __shfl(s, ea),  sb = __shfl(s, eb);
            float aa = __shfl(ex, ea), ab = __shfl(ex, eb);
            f16x8 va = xv[sa * 8 + sub];
            f16x8 vb = xv[sb * 8 + sub];
#pragma unroll
            for (int j = 0; j < 8; ++j) acc[j] = fmaf(aa, (float)va[j], acc[j]);
#pragma unroll
            for (int j = 0; j < 8; ++j) acc[j] = fmaf(ab, (float)vb[j], acc[j]);
        }
        for (; 8 * i < c; ++i) {
            int eidx = 8 * i + grp;
            int   se = __shfl(s, eidx);
            float ae = __shfl(ex, eidx);
            f16x8 v = xv[se * 8 + sub];
#pragma unroll
            for (int j = 0; j < 8; ++j) acc[j] = fmaf(ae, (float)v[j], acc[j]);
        }
    }
#pragma unroll
    for (int off = 32; off; off >>= 1) den += __shfl_xor(den, off);
    const float rd = 1.f / (den + 1e-16f);
#pragma unroll
    for (int j = 0; j < 8; ++j) {
        acc[j] += __shfl_xor(acc[j], 8);
        acc[j] += __shfl_xor(acc[j], 16);
        acc[j] += __shfl_xor(acc[j], 32);
    }
    if (grp == 0) {
        const float4* b4 = (const float4*)bias;
        float4 ba = b4[sub * 2], bb = b4[sub * 2 + 1];
        float4 o0, o1;
        o0.x = fmaf(acc[0], rd, ba.x); o0.y = fmaf(acc[1], rd, ba.y);
        o0.z = fmaf(acc[2], rd, ba.z); o0.w = fmaf(acc[3], rd, ba.w);
        o1.x = fmaf(acc[4], rd, bb.x); o1.y = fmaf(acc[5], rd, bb.y);
        o1.z = fmaf(acc[6], rd, bb.z); o1.w = fmaf(acc[7], rd, bb.w);
        float4* ov = (float4*)out + n * 16 + sub * 2;
        ov[0] = o0; ov[1] = o1;
    }
}

extern "C" void kernel_launch(void* const* d_in, const int* in_sizes, int n_in,
                              void* d_out, int out_size, void* d_ws, size_t ws_size,
                              hipStream_t stream)
{
    (void)in_sizes; (void)n_in; (void)out_size; (void)ws_size;
    const float* x   = (const float*)d_in[0];
    const int*   ei  = (const int*)d_in[1];
    const float* W1  = (const float*)d_in[2];
    const float* as1 = (const float*)d_in[3];
    const float* ad1 = (const float*)d_in[4];
    const float* b1  = (const float*)d_in[5];
    const float* W2  = (const float*)d_in[6];
    const float* as2 = (const float*)d_in[7];
    const float* ad2 = (const float*)d_in[8];
    const float* b2  = (const float*)d_in[9];
    float* out = (float*)d_out;

    // workspace layout (~58 MB)
    f16* xp1h   = (f16*)d_ws;                              // N*256 f16 (25.6 MB)
    f16* hbuf   = xp1h + (size_t)NODES * F1;               // N*256 f16 (25.6 MB)
    f16* W1p    = hbuf + (size_t)NODES * F1;               // 32768 f16
    f16* W2p    = W1p + 32768;                             // 16384 f16
    float* ssrc1 = (float*)(W2p + 16384);                  // N*4
    float* sdst1 = ssrc1 + (size_t)NODES * HEADS;          // N*4
    float* ssrc2 = sdst1 + (size_t)NODES * HEADS;          // N
    float* sdst2 = ssrc2 + (size_t)NODES;                  // N
    int* deg     = (int*)(sdst2 + (size_t)NODES);          // N
    int* row_ptr = deg + NODES;                            // N+1
    int* bsum    = row_ptr + NODES + 1;                    // 256
    int* cursor  = bsum + 256;                             // N
    int* csr_src = cursor + NODES;                         // NE2
    f16* xp2h    = xp1h;   // alias: xp1h dead after k_agg1

    // ---- CSR build (dst-sorted) + W pre-swizzle ----
    hipMemsetAsync(deg, 0, sizeof(int) * NODES, stream);
    k_hist<<<(NEDGE + 255) / 256, 256, 0, stream>>>(ei, deg);
    k_prepW<<<192, 256, 0, stream>>>(W1, W2, W1p, W2p);
    k_scan1<<<NBLK_SCAN, 256, 0, stream>>>(deg, row_ptr, bsum);
    k_scan3<<<NBLK_SCAN, 256, 0, stream>>>(row_ptr, bsum, cursor);
    k_scatter<<<(NE2 + 255) / 256, 256, 0, stream>>>(ei, cursor, csr_src);

    // ---- layer 1 ----
    k_gemm1m<<<(MTILES + 3) / 4, 256, 0, stream>>>(x, W1p, as1, ad1,
                                                   xp1h, ssrc1, sdst1);
    k_agg1<<<NODES / 4, 256, 0, stream>>>(row_ptr, csr_src, ssrc1, sdst1,
                                          xp1h, b1, hbuf);

    // ---- layer 2 ----
    k_gemm2m<<<(MTILES + 3) / 4, 256, 0, stream>>>(hbuf, W2p, as2, ad2,
                                                   xp2h, ssrc2, sdst2);
    k_agg2<<<NODES / 4, 256, 0, stream>>>(row_ptr, csr_src, ssrc2, sdst2,
                                          xp2h, b2, out);
}

// Round 10
// 297.026 us; speedup vs baseline: 5.1255x; 1.0021x over previous
//
#include <hip/hip_runtime.h>
#include <hip/hip_bf16.h>
#include <hip/hip_fp16.h>

// Problem constants (from reference)
#define NODES 50000
#define NEDGE 800000
#define NE2   850000   // NEDGE + NODES self-loops
#define INDIM 128
#define F1    256      // HEADS*HID
#define HEADS 4
#define HID   64
#define OUTD  64
#define NBLK_SCAN 196  // ceil(NODES/256)
#define MTILES 3125    // NODES/16

typedef _Float16 f16;
typedef _Float16 f16x8 __attribute__((ext_vector_type(8)));
typedef float    f32x4 __attribute__((ext_vector_type(4)));

// ================= CSR hist + W pre-swizzle (merged, independent work) ======
__global__ void k_histprep(const int* __restrict__ ei, int* __restrict__ deg,
                           const float* __restrict__ W1, const float* __restrict__ W2,
                           f16* __restrict__ W1p, f16* __restrict__ W2p)
{
    const int b = blockIdx.x, t = threadIdx.x;
    if (b < 3125) {                       // 3125*256 == NEDGE exactly
        int i = b * 256 + t;
        atomicAdd(&deg[ei[NEDGE + i]], 1);
    } else {
        int idx = (b - 3125) * 256 + t;   // < 49152
        if (idx < 32768) {
            int j = idx & 7, l = (idx >> 3) & 63, fi = idx >> 9;
            int kb = fi & 3, ct = fi >> 2;
            int k = kb * 32 + (l >> 4) * 8 + j;
            int col = ct * 16 + (l & 15);
            W1p[idx] = (f16)W1[k * F1 + col];
        } else {
            int i2 = idx - 32768;         // < 16384
            int j = i2 & 7, l = (i2 >> 3) & 63, fi = i2 >> 9;
            int kb = fi & 7, ct = fi >> 3;
            int k = kb * 32 + (l >> 4) * 8 + j;
            int col = ct * 16 + (l & 15);
            W2p[i2] = (f16)W2[k * OUTD + col];
        }
    }
}

// per-256-chunk exclusive scan of (deg+1); chunk total to bsum
__global__ void k_scan1(const int* __restrict__ deg, int* __restrict__ excl,
                        int* __restrict__ bsum)
{
    __shared__ int sh[256];
    int t = threadIdx.x;
    int i = blockIdx.x * 256 + t;
    int v = (i < NODES) ? (deg[i] + 1) : 0;   // +1 = self loop
    sh[t] = v; __syncthreads();
    for (int off = 1; off < 256; off <<= 1) {
        int tv = (t >= off) ? sh[t - off] : 0;
        __syncthreads();
        sh[t] += tv;
        __syncthreads();
    }
    if (i < NODES) excl[i] = sh[t] - v;
    if (t == 255) bsum[blockIdx.x] = sh[255];
}

// add cross-chunk prefix (block-local reduction of bsum[0..bid)) + init cursor
__global__ void k_scan3(int* __restrict__ row_ptr, const int* __restrict__ bsum,
                        int* __restrict__ cursor)
{
    __shared__ int ssum[4];
    const int t = threadIdx.x, wv = t >> 6, lane = t & 63;
    int v = (t < (int)blockIdx.x) ? bsum[t] : 0;
#pragma unroll
    for (int off = 32; off; off >>= 1) v += __shfl_xor(v, off);
    if (lane == 0) ssum[wv] = v;
    __syncthreads();
    int prefix = ssum[0] + ssum[1] + ssum[2] + ssum[3];
    int i = blockIdx.x * 256 + t;
    if (i < NODES) {
        int r = row_ptr[i] + prefix;
        row_ptr[i] = r;
        cursor[i] = r;
    }
    if (i == 0) row_ptr[NODES] = NE2;
}

__global__ void k_scatter(const int* __restrict__ ei, int* __restrict__ cursor,
                          int* __restrict__ csr_src)
{
    int i = blockIdx.x * 256 + threadIdx.x;
    if (i >= NE2) return;
    int s, d;
    if (i < NEDGE) { s = ei[i]; d = ei[NEDGE + i]; } else { s = d = i - NEDGE; }
    int pos = atomicAdd(&cursor[d], 1);
    csr_src[pos] = s;
}

// ====== Layer 1 GEMM (MFMA) + fused attention scores =====================
__global__ __launch_bounds__(256) void k_gemm1m(
    const float* __restrict__ x, const f16* __restrict__ W1p,
    const float* __restrict__ as1, const float* __restrict__ ad1,
    f16* __restrict__ xp1h, float* __restrict__ ssrc, float* __restrict__ sdst)
{
    const int wv = threadIdx.x >> 6, lane = threadIdx.x & 63;
    const int l15 = lane & 15, quad = lane >> 4;
    const int rowtile = blockIdx.x * 4 + wv;
    if (rowtile >= MTILES) return;
    const int rowbase = rowtile * 16;

    f16x8 afrag[4];
    const float* xrow = x + (rowbase + l15) * INDIM + quad * 8;
#pragma unroll
    for (int kb = 0; kb < 4; ++kb) {
        float4 u0 = *(const float4*)(xrow + kb * 32);
        float4 u1 = *(const float4*)(xrow + kb * 32 + 4);
        f16x8 a;
        a[0] = (f16)u0.x; a[1] = (f16)u0.y; a[2] = (f16)u0.z; a[3] = (f16)u0.w;
        a[4] = (f16)u1.x; a[5] = (f16)u1.y; a[6] = (f16)u1.z; a[7] = (f16)u1.w;
        afrag[kb] = a;
    }

    const f16x8* Wf = (const f16x8*)W1p;
    f32x4 acc[16];
#pragma unroll
    for (int ct = 0; ct < 16; ++ct) acc[ct] = (f32x4){0.f, 0.f, 0.f, 0.f};
#pragma unroll
    for (int ct = 0; ct < 16; ++ct) {
#pragma unroll
        for (int kb = 0; kb < 4; ++kb) {
            f16x8 b = Wf[(ct * 4 + kb) * 64 + lane];
            acc[ct] = __builtin_amdgcn_mfma_f32_16x16x32_f16(afrag[kb], b, acc[ct], 0, 0, 0);
        }
    }
    // stores: C/D col = ct*16 + l15, row = quad*4 + r
    const int orow = rowbase + quad * 4;
#pragma unroll
    for (int ct = 0; ct < 16; ++ct) {
#pragma unroll
        for (int r = 0; r < 4; ++r)
            xp1h[(orow + r) * F1 + ct * 16 + l15] = (f16)acc[ct][r];
    }
    // fused scores
    float ps[4][4], pd[4][4];
#pragma unroll
    for (int h = 0; h < 4; ++h)
#pragma unroll
        for (int r = 0; r < 4; ++r) { ps[h][r] = 0.f; pd[h][r] = 0.f; }
#pragma unroll
    for (int ct = 0; ct < 16; ++ct) {
        float av = as1[ct * 16 + l15];
        float dv = ad1[ct * 16 + l15];
        int h = ct >> 2;
#pragma unroll
        for (int r = 0; r < 4; ++r) {
            ps[h][r] = fmaf(acc[ct][r], av, ps[h][r]);
            pd[h][r] = fmaf(acc[ct][r], dv, pd[h][r]);
        }
    }
#pragma unroll
    for (int off = 8; off; off >>= 1) {
#pragma unroll
        for (int h = 0; h < 4; ++h)
#pragma unroll
            for (int r = 0; r < 4; ++r) {
                ps[h][r] += __shfl_xor(ps[h][r], off);
                pd[h][r] += __shfl_xor(pd[h][r], off);
            }
    }
    if (l15 == 0) {
#pragma unroll
        for (int r = 0; r < 4; ++r) {
            int row = orow + r;
            float4 vs = {ps[0][r], ps[1][r], ps[2][r], ps[3][r]};
            float4 vd = {pd[0][r], pd[1][r], pd[2][r], pd[3][r]};
            ((float4*)ssrc)[row] = vs;
            ((float4*)sdst)[row] = vd;
        }
    }
}

// ===== Layer 1 fused softmax+aggregate: ONE wave per node =================
// chunk = 16 edges. Phase A: lane (eq=l&15, ph=l>>4) -> exp(edge eq, head ph).
// Phase B: 4 edges in flight: group g=l>>4 handles edge p+g; 16 lanes x 32B
// (two f16x8 units: sub and sub+16) cover the 512B row. Pads with ex=0.
__global__ __launch_bounds__(256) void k_agg1(
    const int* __restrict__ row_ptr, const int* __restrict__ csr_src,
    const float* __restrict__ ssrc, const float* __restrict__ sdst,
    const f16* __restrict__ xp1h, const float* __restrict__ bias,
    f16* __restrict__ hbuf)
{
    const int wv = threadIdx.x >> 6, l = threadIdx.x & 63;
    const int n = blockIdx.x * 4 + wv;
    const int eq = l & 15, ph = l >> 4;        // phase-A role
    const int g  = l >> 4, sub = l & 15;       // phase-B role
    const int sel_lo = (sub >> 3) << 4;        // head of unit sub (0/1) -> lane blk
    const int sel_hi = (2 + (sub >> 3)) << 4;  // head of unit sub+16 (2/3)
    const float sd = sdst[n * HEADS + ph];
    const int jbeg = row_ptr[n], jend = row_ptr[n + 1];
    const f16x8* xv = (const f16x8*)xp1h;

    float den = 0.f;
    float alo[8] = {0.f,0.f,0.f,0.f,0.f,0.f,0.f,0.f};
    float ahi[8] = {0.f,0.f,0.f,0.f,0.f,0.f,0.f,0.f};
    for (int base = jbeg; base < jend; base += 16) {
        int c = jend - base; if (c > 16) c = 16;
        int s = 0; float ex = 0.f;
        if (eq < c) {
            s = csr_src[base + eq];
            float e = ssrc[s * HEADS + ph] + sd;
            e = e > 0.f ? e : 0.2f * e;
            ex = __expf(e);
        }
        den += ex;
        int p = 0;
        for (; p + 7 < c; p += 8) {            // 8 edges: groups (p..p+3),(p+4..p+7)
            int ea = p + g, eb = p + 4 + g;
            int   sa  = __shfl(s, ea),          sb  = __shfl(s, eb);
            float aal = __shfl(ex, ea | sel_lo), aah = __shfl(ex, ea | sel_hi);
            float abl = __shfl(ex, eb | sel_lo), abh = __shfl(ex, eb | sel_hi);
            f16x8 va0 = xv[sa * 32 + sub];
            f16x8 va1 = xv[sa * 32 + sub + 16];
            f16x8 vb0 = xv[sb * 32 + sub];
            f16x8 vb1 = xv[sb * 32 + sub + 16];
#pragma unroll
            for (int j = 0; j < 8; ++j) {
                alo[j] = fmaf(aal, (float)va0[j], alo[j]);
                ahi[j] = fmaf(aah, (float)va1[j], ahi[j]);
            }
#pragma unroll
            for (int j = 0; j < 8; ++j) {
                alo[j] = fmaf(abl, (float)vb0[j], alo[j]);
                ahi[j] = fmaf(abh, (float)vb1[j], ahi[j]);
            }
        }
        for (; p < c; p += 4) {                // 4 edges, ex=0 pads (s=0 rows L2-hot)
            int ea = p + g;
            int   sa  = __shfl(s, ea);
            float aal = __shfl(ex, ea | sel_lo), aah = __shfl(ex, ea | sel_hi);
            f16x8 va0 = xv[sa * 32 + sub];
            f16x8 va1 = xv[sa * 32 + sub + 16];
#pragma unroll
            for (int j = 0; j < 8; ++j) {
                alo[j] = fmaf(aal, (float)va0[j], alo[j]);
                ahi[j] = fmaf(aah, (float)va1[j], ahi[j]);
            }
        }
    }
    // per-head denominator: reduce within 16-lane groups -> head ph total
#pragma unroll
    for (int off = 8; off; off >>= 1) den += __shfl_xor(den, off);
    const float dl = __shfl(den, sel_lo);
    const float dh = __shfl(den, sel_hi);
    const float rdl = 1.f / (dl + 1e-16f);
    const float rdh = 1.f / (dh + 1e-16f);
    // combine the 4 edge-groups
#pragma unroll
    for (int j = 0; j < 8; ++j) {
        alo[j] += __shfl_xor(alo[j], 16); alo[j] += __shfl_xor(alo[j], 32);
        ahi[j] += __shfl_xor(ahi[j], 16); ahi[j] += __shfl_xor(ahi[j], 32);
    }
    if (g == 0) {
        const float4* b4 = (const float4*)bias;
        float4 bl0 = b4[sub * 2],        bl1 = b4[sub * 2 + 1];
        float4 bh0 = b4[(sub + 16) * 2], bh1 = b4[(sub + 16) * 2 + 1];
        f16x8 olo, ohi;
        float v;
        v = fmaf(alo[0], rdl, bl0.x); olo[0] = (f16)(v > 0.f ? v : 0.f);
        v = fmaf(alo[1], rdl, bl0.y); olo[1] = (f16)(v > 0.f ? v : 0.f);
        v = fmaf(alo[2], rdl, bl0.z); olo[2] = (f16)(v > 0.f ? v : 0.f);
        v = fmaf(alo[3], rdl, bl0.w); olo[3] = (f16)(v > 0.f ? v : 0.f);
        v = fmaf(alo[4], rdl, bl1.x); olo[4] = (f16)(v > 0.f ? v : 0.f);
        v = fmaf(alo[5], rdl, bl1.y); olo[5] = (f16)(v > 0.f ? v : 0.f);
        v = fmaf(alo[6], rdl, bl1.z); olo[6] = (f16)(v > 0.f ? v : 0.f);
        v = fmaf(alo[7], rdl, bl1.w); olo[7] = (f16)(v > 0.f ? v : 0.f);
        v = fmaf(ahi[0], rdh, bh0.x); ohi[0] = (f16)(v > 0.f ? v : 0.f);
        v = fmaf(ahi[1], rdh, bh0.y); ohi[1] = (f16)(v > 0.f ? v : 0.f);
        v = fmaf(ahi[2], rdh, bh0.z); ohi[2] = (f16)(v > 0.f ? v : 0.f);
        v = fmaf(ahi[3], rdh, bh0.w); ohi[3] = (f16)(v > 0.f ? v : 0.f);
        v = fmaf(ahi[4], rdh, bh1.x); ohi[4] = (f16)(v > 0.f ? v : 0.f);
        v = fmaf(ahi[5], rdh, bh1.y); ohi[5] = (f16)(v > 0.f ? v : 0.f);
        v = fmaf(ahi[6], rdh, bh1.z); ohi[6] = (f16)(v > 0.f ? v : 0.f);
        v = fmaf(ahi[7], rdh, bh1.w); ohi[7] = (f16)(v > 0.f ? v : 0.f);
        ((f16x8*)hbuf)[n * 32 + sub] = olo;
        ((f16x8*)hbuf)[n * 32 + sub + 16] = ohi;
    }
}

// ====== Layer 2 GEMM (MFMA) + fused scores ================================
__global__ __launch_bounds__(256) void k_gemm2m(
    const f16* __restrict__ hbuf, const f16* __restrict__ W2p,
    const float* __restrict__ as2, const float* __restrict__ ad2,
    f16* __restrict__ xp2h, float* __restrict__ ssrc, float* __restrict__ sdst)
{
    const int wv = threadIdx.x >> 6, lane = threadIdx.x & 63;
    const int l15 = lane & 15, quad = lane >> 4;
    const int rowtile = blockIdx.x * 4 + wv;
    if (rowtile >= MTILES) return;
    const int rowbase = rowtile * 16;

    const f16x8* Wf = (const f16x8*)W2p;
    f32x4 acc[4];
#pragma unroll
    for (int ct = 0; ct < 4; ++ct) acc[ct] = (f32x4){0.f, 0.f, 0.f, 0.f};
    const f16* hrow = hbuf + (rowbase + l15) * F1 + quad * 8;
#pragma unroll
    for (int kb = 0; kb < 8; ++kb) {
        f16x8 a = *(const f16x8*)(hrow + kb * 32);
#pragma unroll
        for (int ct = 0; ct < 4; ++ct) {
            f16x8 b = Wf[(ct * 8 + kb) * 64 + lane];
            acc[ct] = __builtin_amdgcn_mfma_f32_16x16x32_f16(a, b, acc[ct], 0, 0, 0);
        }
    }
    const int orow = rowbase + quad * 4;
#pragma unroll
    for (int ct = 0; ct < 4; ++ct) {
#pragma unroll
        for (int r = 0; r < 4; ++r)
            xp2h[(orow + r) * OUTD + ct * 16 + l15] = (f16)acc[ct][r];
    }
    float ps[4] = {0.f,0.f,0.f,0.f}, pd[4] = {0.f,0.f,0.f,0.f};
#pragma unroll
    for (int ct = 0; ct < 4; ++ct) {
        float av = as2[ct * 16 + l15];
        float dv = ad2[ct * 16 + l15];
#pragma unroll
        for (int r = 0; r < 4; ++r) {
            ps[r] = fmaf(acc[ct][r], av, ps[r]);
            pd[r] = fmaf(acc[ct][r], dv, pd[r]);
        }
    }
#pragma unroll
    for (int off = 8; off; off >>= 1) {
#pragma unroll
        for (int r = 0; r < 4; ++r) {
            ps[r] += __shfl_xor(ps[r], off);
            pd[r] += __shfl_xor(pd[r], off);
        }
    }
    if (l15 == 0) {
#pragma unroll
        for (int r = 0; r < 4; ++r) {
            ssrc[orow + r] = ps[r];
            sdst[orow + r] = pd[r];
        }
    }
}

// ===== Layer 2 fused softmax+aggregate+bias -> d_out: b128 gather =====
// chunk = 64 edges; phase B 2-step unroll (2 gathers in flight per lane)
__global__ __launch_bounds__(256) void k_agg2(
    const int* __restrict__ row_ptr, const int* __restrict__ csr_src,
    const float* __restrict__ ssrc, const float* __restrict__ sdst,
    const f16* __restrict__ xp2h, const float* __restrict__ bias,
    float* __restrict__ out)
{
    const int wv = threadIdx.x >> 6, l = threadIdx.x & 63;
    const int n = blockIdx.x * 4 + wv;
    const int grp = l >> 3, sub = l & 7;
    const float sd = sdst[n];
    const int jbeg = row_ptr[n], jend = row_ptr[n + 1];
    const f16x8* xv = (const f16x8*)xp2h;

    float den = 0.f;
    float acc[8] = {0.f,0.f,0.f,0.f,0.f,0.f,0.f,0.f};
    for (int base = jbeg; base < jend; base += 64) {
        int c = jend - base; if (c > 64) c = 64;
        int s = 0; float ex = 0.f;
        if (l < c) {
            s = csr_src[base + l];
            float e = ssrc[s] + sd;
            e = e > 0.f ? e : 0.2f * e;
            ex = __expf(e);
        }
        den += ex;
        int i = 0;
        for (; 8 * (i + 1) < c; i += 2) {
            int ea = 8 * i + grp, eb = 8 * i + 8 + grp;
            int   sa = __shfl(s, ea),  sb = __shfl(s, eb);
            float aa = __shfl(ex, ea), ab = __shfl(ex, eb);
            f16x8 va = xv[sa * 8 + sub];
            f16x8 vb = xv[sb * 8 + sub];
#pragma unroll
            for (int j = 0; j < 8; ++j) acc[j] = fmaf(aa, (float)va[j], acc[j]);
#pragma unroll
            for (int j = 0; j < 8; ++j) acc[j] = fmaf(ab, (float)vb[j], acc[j]);
        }
        for (; 8 * i < c; ++i) {
            int eidx = 8 * i + grp;
            int   se = __shfl(s, eidx);
            float ae = __shfl(ex, eidx);
            f16x8 v = xv[se * 8 + sub];
#pragma unroll
            for (int j = 0; j < 8; ++j) acc[j] = fmaf(ae, (float)v[j], acc[j]);
        }
    }
#pragma unroll
    for (int off = 32; off; off >>= 1) den += __shfl_xor(den, off);
    const float rd = 1.f / (den + 1e-16f);
#pragma unroll
    for (int j = 0; j < 8; ++j) {
        acc[j] += __shfl_xor(acc[j], 8);
        acc[j] += __shfl_xor(acc[j], 16);
        acc[j] += __shfl_xor(acc[j], 32);
    }
    if (grp == 0) {
        const float4* b4 = (const float4*)bias;
        float4 ba = b4[sub * 2], bb = b4[sub * 2 + 1];
        float4 o0, o1;
        o0.x = fmaf(acc[0], rd, ba.x); o0.y = fmaf(acc[1], rd, ba.y);
        o0.z = fmaf(acc[2], rd, ba.z); o0.w = fmaf(acc[3], rd, ba.w);
        o1.x = fmaf(acc[4], rd, bb.x); o1.y = fmaf(acc[5], rd, bb.y);
        o1.z = fmaf(acc[6], rd, bb.z); o1.w = fmaf(acc[7], rd, bb.w);
        float4* ov = (float4*)out + n * 16 + sub * 2;
        ov[0] = o0; ov[1] = o1;
    }
}

extern "C" void kernel_launch(void* const* d_in, const int* in_sizes, int n_in,
                              void* d_out, int out_size, void* d_ws, size_t ws_size,
                              hipStream_t stream)
{
    (void)in_sizes; (void)n_in; (void)out_size; (void)ws_size;
    const float* x   = (const float*)d_in[0];
    const int*   ei  = (const int*)d_in[1];
    const float* W1  = (const float*)d_in[2];
    const float* as1 = (const float*)d_in[3];
    const float* ad1 = (const float*)d_in[4];
    const float* b1  = (const float*)d_in[5];
    const float* W2  = (const float*)d_in[6];
    const float* as2 = (const float*)d_in[7];
    const float* ad2 = (const float*)d_in[8];
    const float* b2  = (const float*)d_in[9];
    float* out = (float*)d_out;

    // workspace layout (~58 MB)
    f16* xp1h   = (f16*)d_ws;                              // N*256 f16 (25.6 MB)
    f16* hbuf   = xp1h + (size_t)NODES * F1;               // N*256 f16 (25.6 MB)
    f16* W1p    = hbuf + (size_t)NODES * F1;               // 32768 f16
    f16* W2p    = W1p + 32768;                             // 16384 f16
    float* ssrc1 = (float*)(W2p + 16384);                  // N*4
    float* sdst1 = ssrc1 + (size_t)NODES * HEADS;          // N*4
    float* ssrc2 = sdst1 + (size_t)NODES * HEADS;          // N
    float* sdst2 = ssrc2 + (size_t)NODES;                  // N
    int* deg     = (int*)(sdst2 + (size_t)NODES);          // N
    int* row_ptr = deg + NODES;                            // N+1
    int* bsum    = row_ptr + NODES + 1;                    // 256
    int* cursor  = bsum + 256;                             // N
    int* csr_src = cursor + NODES;                         // NE2
    f16* xp2h    = xp1h;   // alias: xp1h dead after k_agg1

    // ---- CSR build (dst-sorted) + W pre-swizzle ----
    hipMemsetAsync(deg, 0, sizeof(int) * NODES, stream);
    k_histprep<<<3125 + 192, 256, 0, stream>>>(ei, deg, W1, W2, W1p, W2p);
    k_scan1<<<NBLK_SCAN, 256, 0, stream>>>(deg, row_ptr, bsum);
    k_scan3<<<NBLK_SCAN, 256, 0, stream>>>(row_ptr, bsum, cursor);
    k_scatter<<<(NE2 + 255) / 256, 256, 0, stream>>>(ei, cursor, csr_src);

    // ---- layer 1 ----
    k_gemm1m<<<(MTILES + 3) / 4, 256, 0, stream>>>(x, W1p, as1, ad1,
                                                   xp1h, ssrc1, sdst1);
    k_agg1<<<NODES / 4, 256, 0, stream>>>(row_ptr, csr_src, ssrc1, sdst1,
                                          xp1h, b1, hbuf);

    // ---- layer 2 ----
    k_gemm2m<<<(MTILES + 3) / 4, 256, 0, stream>>>(hbuf, W2p, as2, ad2,
                                                   xp2h, ssrc2, sdst2);
    k_agg2<<<NODES / 4, 256, 0, stream>>>(row_ptr, csr_src, ssrc2, sdst2,
                                          xp2h, b2, out);
}